// Round 8
// baseline (326.867 us; speedup 1.0000x reference)
//
#include <hip/hip_runtime.h>
#include <hip/hip_bf16.h>
#include <hip/hip_fp16.h>

// GCN2: 3x GCNConv(relu,relu,none) + global_mean_pool + linear head.
// R8: (1) layer-2 GEMM -> MFMA f16 (A from global, W2T in LDS, fp32 acc),
// h1 stored fp16. (2) hsh stored slice-major (8 slices of [N,16] fp16,
// 1.6MB each); agg128s pins slice = blockIdx%8 -> per-XCD L2-resident
// gather working set (slice + csr16 < 4MB XCD L2). CSR build unchanged (R7).

#define HIDDEN 128
#define F_IN 11
#define NCLS 19
#define NBITS 9
#define NB 128
#define RNODES 512
#define EPB 8192

typedef _Float16 half8 __attribute__((ext_vector_type(8)));
typedef float floatx4 __attribute__((ext_vector_type(4)));

// ---------------- bucketed CSR build ----------------

__global__ void hist_kernel(const int* __restrict__ dst, int* __restrict__ bhist, int E) {
    __shared__ int h[NB];
    int tid = threadIdx.x;
    for (int i = tid; i < NB; i += 256) h[i] = 0;
    __syncthreads();
    int lim = min((blockIdx.x + 1) * EPB, E);
    for (int e = blockIdx.x * EPB + tid; e < lim; e += 256)
        atomicAdd(&h[dst[e] >> NBITS], 1);
    __syncthreads();
    for (int i = tid; i < NB; i += 256) if (h[i]) atomicAdd(&bhist[i], h[i]);
}

__global__ void bucket_scan_kernel(const int* __restrict__ bhist, int* __restrict__ bstart,
                                   int* __restrict__ bcur, int* __restrict__ offs,
                                   int n, int E) {
    __shared__ int cw[2];
    int tid = threadIdx.x, lane = tid & 63, w = tid >> 6;
    int v = bhist[tid], xv = v;
#pragma unroll
    for (int d = 1; d < 64; d <<= 1) {
        int t = __shfl_up(xv, d, 64);
        if (lane >= d) xv += t;
    }
    if (lane == 63) cw[w] = xv;
    __syncthreads();
    int excl = xv - v + ((w == 1) ? cw[0] : 0);
    bstart[tid] = excl;
    bcur[tid] = excl;
    if (tid == 127) bstart[128] = excl + v;
    if (tid == 0) offs[n] = E + n;
}

__global__ void scatter_kernel(const int* __restrict__ src, const int* __restrict__ dst,
                               int* __restrict__ bcur, unsigned int* __restrict__ bents, int E) {
    __shared__ int hist[NB];
    __shared__ int binoff[NB];
    __shared__ int runbase[NB];
    __shared__ unsigned int ebuf[EPB];
    __shared__ unsigned short binOf[EPB];
    __shared__ int cw[2];
    int tid = threadIdx.x, lane = tid & 63, w = tid >> 6;
    int base = blockIdx.x * EPB;
    int cnt = min(EPB, E - base);
    for (int i = tid; i < NB; i += 256) hist[i] = 0;
    __syncthreads();
    unsigned int pk[32];
    int rk[32];
#pragma unroll
    for (int j = 0; j < 32; ++j) {
        int idx = tid + 256 * j;
        if (idx < cnt) {
            int e = base + idx;
            int s = src[e], d = dst[e];
            pk[j] = (unsigned int)s | ((unsigned int)d << 16);
            int bin = d >> NBITS;
            int r = atomicAdd(&hist[bin], 1);
            rk[j] = r | (bin << 16);
        } else rk[j] = -1;
    }
    __syncthreads();
    int v = 0, xv = 0;
    if (tid < NB) {
        v = hist[tid]; xv = v;
#pragma unroll
        for (int d = 1; d < 64; d <<= 1) {
            int t = __shfl_up(xv, d, 64);
            if (lane >= d) xv += t;
        }
        if (lane == 63) cw[w] = xv;
    }
    __syncthreads();
    if (tid < NB) {
        binoff[tid] = xv - v + ((w == 1) ? cw[0] : 0);
        runbase[tid] = v ? atomicAdd(&bcur[tid], v) : 0;
    }
    __syncthreads();
#pragma unroll
    for (int j = 0; j < 32; ++j) {
        if (rk[j] >= 0) {
            int bin = rk[j] >> 16, r = rk[j] & 0xFFFF;
            int pos = binoff[bin] + r;
            ebuf[pos] = pk[j];
            binOf[pos] = (unsigned short)bin;
        }
    }
    __syncthreads();
    for (int i = tid; i < cnt; i += 256) {
        int bin = binOf[i];
        bents[runbase[bin] + (i - binoff[bin])] = ebuf[i];
    }
}

__global__ void build_kernel(const unsigned int* __restrict__ bents, const int* __restrict__ bstart,
                             const float* __restrict__ x, const int* __restrict__ batch,
                             int* __restrict__ offs, unsigned short* __restrict__ csr16,
                             float* __restrict__ dinv, float* __restrict__ gcnt,
                             float* __restrict__ x16, int n) {
    __shared__ int counts[RNODES];
    __shared__ int lcur[RNODES];
    __shared__ unsigned short outl[13824];
    __shared__ int wsums[8];
    int tid = threadIdx.x;          // 1024
    int lane = tid & 63, w = tid >> 6;
    int b = blockIdx.x;
    int base = b << NBITS;
    int nn = min(RNODES, n - base);
    int ebase = bstart[b], ecnt = bstart[b + 1] - ebase;
    for (int i = tid; i < RNODES; i += 1024) counts[i] = 0;
    __syncthreads();
    for (int e = tid; e < ecnt; e += 1024)
        atomicAdd(&counts[(bents[ebase + e] >> 16) - base], 1);
    __syncthreads();
    int v = 0, xv = 0;
    if (tid < RNODES) {
        v = (tid < nn) ? counts[tid] + 1 : 0;
        xv = v;
#pragma unroll
        for (int d = 1; d < 64; d <<= 1) {
            int t = __shfl_up(xv, d, 64);
            if (lane >= d) xv += t;
        }
        if (lane == 63) wsums[w] = xv;
    }
    __syncthreads();
    if (tid < 64) {
        int s = (lane < 8) ? wsums[lane] : 0;
#pragma unroll
        for (int d = 1; d < 8; d <<= 1) {
            int t = __shfl_up(s, d, 64);
            if (lane >= d) s += t;
        }
        if (lane < 8) wsums[lane] = s;
    }
    __syncthreads();
    if (tid < nn) {
        int excl = xv - v + ((w > 0) ? wsums[w - 1] : 0);
        lcur[tid] = excl + 1;
        outl[excl] = (unsigned short)(base + tid);        // self-loop slot 0
        offs[base + tid] = ebase + base + excl;
        atomicAdd(&gcnt[batch[base + tid]], 1.0f);
    }
    __syncthreads();
    for (int e = tid; e < ecnt; e += 1024) {
        unsigned int pk = bents[ebase + e];
        int i = (int)(pk >> 16) - base;
        int r = atomicAdd(&lcur[i], 1);
        outl[r] = (unsigned short)(pk & 0xFFFFu);
    }
    __syncthreads();
    int total = ecnt + nn;
    for (int i = tid; i < total; i += 1024)
        csr16[ebase + base + i] = outl[i];
    for (int idx = tid; idx < nn * 16; idx += 1024) {
        int i = idx >> 4, j = idx & 15;
        float di = 1.0f / sqrtf((float)(counts[i] + 1));
        if (j == 0) dinv[base + i] = di;
        x16[(long)(base + i) * 16 + j] = (j < F_IN) ? x[(long)(base + i) * F_IN + j] * di : 0.f;
    }
}

// ---------------- layer 1 ----------------

__global__ void agg16_kernel(const float* __restrict__ xs, const int* __restrict__ offs,
                             const unsigned short* __restrict__ csr16, const float* __restrict__ dinv,
                             float* __restrict__ z16, int n) {
    int node = (int)(((long)blockIdx.x * blockDim.x + threadIdx.x) >> 6);
    int lane = threadIdx.x & 63;
    if (node >= n) return;
    int grp = lane >> 4, f = lane & 15;
    int beg = offs[node], end = offs[node + 1];
    float acc = 0.f;
    int eb = beg;
    for (; eb + 16 <= end; eb += 16) {
        int s[4]; float v[4];
#pragma unroll
        for (int j = 0; j < 4; ++j) s[j] = csr16[eb + grp + 4 * j];
#pragma unroll
        for (int j = 0; j < 4; ++j) v[j] = xs[(long)s[j] * 16 + f];
#pragma unroll
        for (int j = 0; j < 4; ++j) acc += v[j];
    }
    if (eb + 8 <= end) {
        int s0 = csr16[eb + grp], s1 = csr16[eb + grp + 4];
        acc += xs[(long)s0 * 16 + f] + xs[(long)s1 * 16 + f];
        eb += 8;
    }
    for (int e = eb + grp; e < end; e += 4)
        acc += xs[(long)csr16[e] * 16 + f];
    acc += __shfl_down(acc, 32);
    acc += __shfl_down(acc, 16);
    if (lane < 16) z16[(long)node * 16 + lane] = acc * dinv[node];
}

// h1 = relu(z16[:, :11] @ W1 + b1) -> fp16; 8 nodes per 256-thread block
__global__ void gemm_in_kernel(const float* __restrict__ z16, const float* __restrict__ W1,
                               const float* __restrict__ b1, __half* __restrict__ out, int n) {
    __shared__ float Ws[F_IN * HIDDEN];
    __shared__ float bs[HIDDEN];
    __shared__ float zs[8][16];
    int tid = threadIdx.x;
    long base = (long)blockIdx.x * 8;
    for (int i = tid; i < F_IN * HIDDEN; i += 256) Ws[i] = W1[i];
    if (tid < HIDDEN) bs[tid] = b1[tid];
    if (tid < 128) {
        int ln = tid >> 4, f = tid & 15;
        long gn = base + ln;
        zs[ln][f] = (gn < n) ? z16[gn * 16 + f] : 0.f;
    }
    __syncthreads();
    int f = tid & 127, half_ = tid >> 7;
#pragma unroll
    for (int r = 0; r < 4; ++r) {
        int ln = half_ * 4 + r;
        long gn = base + ln;
        float acc = bs[f];
#pragma unroll
        for (int k = 0; k < F_IN; ++k) acc += zs[ln][k] * Ws[k * HIDDEN + f];
        if (gn < n) out[gn * HIDDEN + f] = __float2half(fmaxf(acc, 0.f));
    }
}

// ---------------- layer-2 GEMM: MFMA f16, slice-major fp16 output ----------------
// 64 nodes/block, 4 waves x 16 nodes; A from global (h1 fp16 rows), W2T in LDS.

__global__ __launch_bounds__(256) void gemm_mfma_kernel(
        const __half* __restrict__ h1h, const float* __restrict__ W2,
        const float* __restrict__ dinv, __half* __restrict__ hsh, int n) {
    __shared__ _Float16 W2T[128 * 136];    // [n][k], stride 136
    __shared__ _Float16 outs[64 * 132];    // [node][feat], stride 132
    int tid = threadIdx.x;
    for (int i = tid; i < 128 * 128; i += 256) {
        int k = i >> 7, nn = i & 127;
        W2T[nn * 136 + k] = (_Float16)W2[i];
    }
    int base = blockIdx.x * 64;
    int lane = tid & 63, wid = tid >> 6;
    int l15 = lane & 15, quad = lane >> 4;
    int arow = base + wid * 16 + l15;
    if (arow >= n) arow = n - 1;           // clamp: safe reads, invalid rows unwritten
    const _Float16* Aptr = (const _Float16*)h1h + (size_t)arow * 128;
    floatx4 acc[8];
#pragma unroll
    for (int t = 0; t < 8; ++t) acc[t] = (floatx4){0.f, 0.f, 0.f, 0.f};
    __syncthreads();
#pragma unroll
    for (int c = 0; c < 4; ++c) {
        half8 a = *(const half8*)(Aptr + c * 32 + quad * 8);
#pragma unroll
        for (int t = 0; t < 8; ++t) {
            half8 b = *(const half8*)(&W2T[(t * 16 + l15) * 136 + c * 32 + quad * 8]);
            acc[t] = __builtin_amdgcn_mfma_f32_16x16x32_f16(a, b, acc[t], 0, 0, 0);
        }
    }
    // D layout: row(m)=quad*4+reg, col(n)=l15  (node=row, feat=col)
    float dv[4];
#pragma unroll
    for (int r = 0; r < 4; ++r) {
        int nd = base + wid * 16 + quad * 4 + r;
        dv[r] = dinv[(nd < n) ? nd : 0];
    }
#pragma unroll
    for (int t = 0; t < 8; ++t)
#pragma unroll
        for (int r = 0; r < 4; ++r)
            outs[(wid * 16 + quad * 4 + r) * 132 + t * 16 + l15] = (_Float16)(acc[t][r] * dv[r]);
    __syncthreads();
    // copy out slice-major: hsh[slice][node][16 halves]; uint2 = 4 halves
    int ln = tid >> 2, q = tid & 3;
    long nd = base + ln;
    if (nd < n) {
#pragma unroll
        for (int s = 0; s < 8; ++s) {
            uint2 u = *(uint2*)&outs[ln * 132 + s * 16 + q * 4];
            ((uint2*)hsh)[((size_t)s * n + nd) * 4 + q] = u;
        }
    }
}

// ---------------- layer-2 agg: per-slice, XCD-pinned (slice = blockIdx%8) ----------------

__global__ void agg128s_kernel(const __half* __restrict__ hsh, const int* __restrict__ offs,
                               const unsigned short* __restrict__ csr16,
                               const float* __restrict__ dinv, const float* __restrict__ bias,
                               float* __restrict__ out, int n) {
    int s = blockIdx.x & 7;
    int node = (blockIdx.x >> 3) * 4 + (threadIdx.x >> 6);
    int lane = threadIdx.x & 63;
    if (node >= n) return;
    int grp = lane >> 3, f8 = lane & 7;
    const unsigned int* hs = (const unsigned int*)hsh + (size_t)s * n * 8;  // 8 uints/row
    int beg = offs[node], end = offs[node + 1];
    float2 acc = {0.f, 0.f};
    int eb = beg;
    for (; eb + 32 <= end; eb += 32) {
        int sv[4]; unsigned int u[4];
#pragma unroll
        for (int j = 0; j < 4; ++j) sv[j] = csr16[eb + grp + 8 * j];
#pragma unroll
        for (int j = 0; j < 4; ++j) u[j] = hs[(size_t)sv[j] * 8 + f8];
#pragma unroll
        for (int j = 0; j < 4; ++j) {
            float2 v = __half22float2(*(__half2*)&u[j]);
            acc.x += v.x; acc.y += v.y;
        }
    }
    if (eb + 16 <= end) {
        int sv[2]; unsigned int u[2];
#pragma unroll
        for (int j = 0; j < 2; ++j) sv[j] = csr16[eb + grp + 8 * j];
#pragma unroll
        for (int j = 0; j < 2; ++j) u[j] = hs[(size_t)sv[j] * 8 + f8];
#pragma unroll
        for (int j = 0; j < 2; ++j) {
            float2 v = __half22float2(*(__half2*)&u[j]);
            acc.x += v.x; acc.y += v.y;
        }
        eb += 16;
    }
    for (int e = eb + grp; e < end; e += 8) {
        unsigned int u = hs[(size_t)csr16[e] * 8 + f8];
        float2 v = __half22float2(*(__half2*)&u);
        acc.x += v.x; acc.y += v.y;
    }
    acc.x += __shfl_down(acc.x, 32); acc.y += __shfl_down(acc.y, 32);
    acc.x += __shfl_down(acc.x, 16); acc.y += __shfl_down(acc.y, 16);
    acc.x += __shfl_down(acc.x, 8);  acc.y += __shfl_down(acc.y, 8);
    if (lane < 8) {
        float di = dinv[node];
        float2 b = ((const float2*)bias)[s * 8 + lane];
        float2 r;
        r.x = fmaxf(acc.x * di + b.x, 0.f);
        r.y = fmaxf(acc.y * di + b.y, 0.f);
        ((float2*)(out + (size_t)node * HIDDEN + s * 16))[lane] = r;
    }
}

// ---------------- folded layer 3 + pool + head ----------------

__global__ void w3l_kernel(const float* __restrict__ W3, const float* __restrict__ Wl,
                           const float* __restrict__ b3, float* __restrict__ W3l,
                           float* __restrict__ b3l) {
    __shared__ float Wls[HIDDEN * NCLS];
    int tid = threadIdx.x;
    for (int i = tid; i < HIDDEN * NCLS; i += 256) Wls[i] = Wl[i];
    __syncthreads();
    if (blockIdx.x < 10) {
        int o = blockIdx.x * 256 + tid;
        if (o < HIDDEN * NCLS) {
            int i = o / NCLS, j = o % NCLS;
            float acc = 0.f;
#pragma unroll 8
            for (int k = 0; k < HIDDEN; ++k) acc += W3[i * HIDDEN + k] * Wls[k * NCLS + j];
            W3l[o] = acc;
        }
    } else if (tid < NCLS) {
        float acc = 0.f;
#pragma unroll 8
        for (int k = 0; k < HIDDEN; ++k) acc += b3[k] * Wls[k * NCLS + tid];
        b3l[tid] = acc;
    }
}

__global__ void gemm_y32h_kernel(const float* __restrict__ h2, const float* __restrict__ W3l,
                                 const float* __restrict__ dinv, __half* __restrict__ ys, int n) {
    __shared__ float hs[12][HIDDEN];
    __shared__ float Ws[HIDDEN][20];
    int tid = threadIdx.x;
    long base = (long)blockIdx.x * 12;
    for (int i = tid; i < HIDDEN * NCLS; i += 256) Ws[i / NCLS][i % NCLS] = W3l[i];
    for (int idx = tid; idx < 12 * 32; idx += 256) {
        int node = idx >> 5, q = idx & 31;
        long gn = base + node;
        float4 a = (gn < n) ? ((const float4*)(h2 + gn * HIDDEN))[q]
                            : make_float4(0.f, 0.f, 0.f, 0.f);
        *(float4*)&hs[node][q * 4] = a;
    }
    __syncthreads();
    if (tid < 12 * NCLS) {
        int node = tid / NCLS, j = tid % NCLS;
        long gn = base + node;
        if (gn < n) {
            float acc = 0.f;
#pragma unroll 8
            for (int k = 0; k < HIDDEN; ++k) acc += hs[node][k] * Ws[k][j];
            ys[gn * 32 + j] = __float2half(acc * dinv[gn]);
        }
    }
    for (int idx = tid; idx < 12 * 13; idx += 256) {
        int node = idx / 13, j = 19 + idx % 13;
        long gn = base + node;
        if (gn < n) ys[gn * 32 + j] = __half(0.f);
    }
}

__global__ void agg24h_pool_kernel(const __half* __restrict__ ys, const int* __restrict__ offs,
                                   const unsigned short* __restrict__ csr16, const float* __restrict__ dinv,
                                   const int* __restrict__ batch, float* __restrict__ pool, int n) {
    int node = (int)(((long)blockIdx.x * blockDim.x + threadIdx.x) >> 6);
    int lane = threadIdx.x & 63;
    if (node >= n) return;
    int grp = lane >> 4, f = lane & 15;
    int beg = offs[node], end = offs[node + 1];
    float2 acc = {0.f, 0.f};
    int eb = beg;
    for (; eb + 32 <= end; eb += 32) {
        int s[8]; unsigned int u[8];
#pragma unroll
        for (int j = 0; j < 8; ++j) s[j] = csr16[eb + grp + 4 * j];
#pragma unroll
        for (int j = 0; j < 8; ++j) u[j] = ((const unsigned int*)ys)[(long)s[j] * 16 + f];
#pragma unroll
        for (int j = 0; j < 8; ++j) {
            float2 v = __half22float2(*(__half2*)&u[j]);
            acc.x += v.x; acc.y += v.y;
        }
    }
    if (eb + 16 <= end) {
        int s[4]; unsigned int u[4];
#pragma unroll
        for (int j = 0; j < 4; ++j) s[j] = csr16[eb + grp + 4 * j];
#pragma unroll
        for (int j = 0; j < 4; ++j) u[j] = ((const unsigned int*)ys)[(long)s[j] * 16 + f];
#pragma unroll
        for (int j = 0; j < 4; ++j) {
            float2 v = __half22float2(*(__half2*)&u[j]);
            acc.x += v.x; acc.y += v.y;
        }
        eb += 16;
    }
    for (int e = eb + grp; e < end; e += 4) {
        unsigned int u = ((const unsigned int*)ys)[(long)csr16[e] * 16 + f];
        float2 v = __half22float2(*(__half2*)&u);
        acc.x += v.x; acc.y += v.y;
    }
    acc.x += __shfl_down(acc.x, 32);
    acc.y += __shfl_down(acc.y, 32);
    acc.x += __shfl_down(acc.x, 16);
    acc.y += __shfl_down(acc.y, 16);
    if (lane < 16) {
        int g = batch[node];
        float sc = dinv[node];
        int c0 = 2 * f;
        if (c0 < NCLS) atomicAdd(&pool[(long)g * 24 + c0], acc.x * sc);
        if (c0 + 1 < NCLS) atomicAdd(&pool[(long)g * 24 + c0 + 1], acc.y * sc);
    }
}

__global__ void final_kernel(const float* __restrict__ pool, const float* __restrict__ cnt,
                             const float* __restrict__ b3l, const float* __restrict__ bl,
                             float* __restrict__ out, int G) {
    int i = blockIdx.x * blockDim.x + threadIdx.x;
    if (i >= G * NCLS) return;
    int g = i / NCLS, j = i % NCLS;
    float c = cnt[g];
    out[i] = (c > 0.f) ? pool[(long)g * 24 + j] / c + b3l[j] + bl[j] : bl[j];
}

// ---------------- launch ----------------

static inline size_t align256(size_t x) { return (x + 255) & ~(size_t)255; }

extern "C" void kernel_launch(void* const* d_in, const int* in_sizes, int n_in,
                              void* d_out, int out_size, void* d_ws, size_t ws_size,
                              hipStream_t stream) {
    const float* x    = (const float*)d_in[0];
    const int*   ei   = (const int*)d_in[1];
    const int*   batch= (const int*)d_in[2];
    const float* W1   = (const float*)d_in[3];
    const float* b1   = (const float*)d_in[4];
    const float* W2   = (const float*)d_in[5];
    const float* b2   = (const float*)d_in[6];
    const float* W3   = (const float*)d_in[7];
    const float* b3   = (const float*)d_in[8];
    const float* Wl   = (const float*)d_in[9];
    const float* bl   = (const float*)d_in[10];
    float* out = (float*)d_out;

    const int N = in_sizes[0] / F_IN;
    const int E = in_sizes[1] / 2;
    const int G = out_size / NCLS;
    const int* src = ei;
    const int* dst = ei + E;
    const int nSB = (E + EPB - 1) / EPB;
    const int nBK = (N + RNODES - 1) / RNODES;

    // workspace carve-up
    char* p = (char*)d_ws;
    size_t off = 0;
    int*            bhist  = (int*)(p + off);            off = align256(off + NB * 4);
    int*            bstart = (int*)(p + off);            off = align256(off + (NB + 1) * 4);
    int*            bcur   = (int*)(p + off);            off = align256(off + NB * 4);
    unsigned int*   bents  = (unsigned int*)(p + off);   off = align256(off + (size_t)E * 4);
    unsigned short* csr16  = (unsigned short*)(p + off); off = align256(off + (size_t)(E + N) * 2);
    int*            offs   = (int*)(p + off);            off = align256(off + (size_t)(N + 1) * 4);
    float*          dinv   = (float*)(p + off);          off = align256(off + (size_t)N * 4);
    float*          x16    = (float*)(p + off);          off = align256(off + (size_t)N * 16 * 4);
    float*          z16    = (float*)(p + off);          off = align256(off + (size_t)N * 16 * 4);
    __half*         h1h    = (__half*)(p + off);         off = align256(off + (size_t)N * HIDDEN * 2);
    __half*         hsh    = (__half*)(p + off);         off = align256(off + (size_t)N * HIDDEN * 2);
    __half*         y32h   = (__half*)(p + off);         off = align256(off + (size_t)N * 32 * 2);
    float*          W3l    = (float*)(p + off);          off = align256(off + (size_t)HIDDEN * NCLS * 4);
    float*          b3l    = (float*)(p + off);          off = align256(off + (size_t)NCLS * 4);
    float*          pool   = (float*)(p + off);          off = align256(off + (size_t)G * 25 * 4);
    float*          gcnt   = pool + (size_t)G * 24;
    float*          h_a    = (float*)(p + off);          off = align256(off + (size_t)N * HIDDEN * 4);
    (void)ws_size; (void)n_in;

    hipMemsetAsync(bhist, 0, NB * 4, stream);
    hipMemsetAsync(pool, 0, (size_t)G * 25 * 4, stream);

    // bucketed CSR build
    hist_kernel<<<nSB, 256, 0, stream>>>(dst, bhist, E);
    bucket_scan_kernel<<<1, 128, 0, stream>>>(bhist, bstart, bcur, offs, N, E);
    scatter_kernel<<<nSB, 256, 0, stream>>>(src, dst, bcur, bents, E);
    build_kernel<<<nBK, 1024, 0, stream>>>(bents, bstart, x, batch, offs, csr16,
                                           dinv, gcnt, x16, N);
    w3l_kernel<<<11, 256, 0, stream>>>(W3, Wl, b3, W3l, b3l);

    const int aggBlocks = (N + 3) / 4;  // 4 waves/block, wave per node

    // layer 1: z16 = dinv * sum(x16) ; h1 = relu(z16@W1+b1) -> fp16
    agg16_kernel<<<aggBlocks, 256, 0, stream>>>(x16, offs, csr16, dinv, z16, N);
    gemm_in_kernel<<<(N + 7) / 8, 256, 0, stream>>>(z16, W1, b1, h1h, N);

    // layer 2: hsh = half((h1@W2)*dinv) slice-major [MFMA] ; h2 = relu(dinv*sum + b2)
    gemm_mfma_kernel<<<(N + 63) / 64, 256, 0, stream>>>(h1h, W2, dinv, hsh, N);
    agg128s_kernel<<<((N + 3) / 4) * 8, 256, 0, stream>>>(hsh, offs, csr16, dinv, b2, h_a, N);

    // folded layer 3 + pool
    gemm_y32h_kernel<<<(N + 11) / 12, 256, 0, stream>>>(h_a, W3l, dinv, y32h, N);
    agg24h_pool_kernel<<<aggBlocks, 256, 0, stream>>>(y32h, offs, csr16, dinv, batch, pool, N);
    final_kernel<<<(G * NCLS + 255) / 256, 256, 0, stream>>>(pool, gcnt, b3l, bl, out, G);
}

// Round 9
// 264.869 us; speedup vs baseline: 1.2341x; 1.2341x over previous
//
#include <hip/hip_runtime.h>
#include <hip/hip_bf16.h>
#include <hip/hip_fp16.h>

// GCN2: 3x GCNConv(relu,relu,none) + global_mean_pool + linear head.
// R9: best-of R7+R8. MFMA f16 layer-2 GEMM (R8) kept but emits ROW-major
// [N,128] fp16; layer-2 agg reverts to R7's agg128h (slice-major agg128s
// was instruction-bound: 8x edge-index replication, VALUBusy 47%, 102us).

#define HIDDEN 128
#define F_IN 11
#define NCLS 19
#define NBITS 9
#define NB 128
#define RNODES 512
#define EPB 8192

typedef _Float16 half8 __attribute__((ext_vector_type(8)));
typedef float floatx4 __attribute__((ext_vector_type(4)));

// ---------------- bucketed CSR build ----------------

__global__ void hist_kernel(const int* __restrict__ dst, int* __restrict__ bhist, int E) {
    __shared__ int h[NB];
    int tid = threadIdx.x;
    for (int i = tid; i < NB; i += 256) h[i] = 0;
    __syncthreads();
    int lim = min((blockIdx.x + 1) * EPB, E);
    for (int e = blockIdx.x * EPB + tid; e < lim; e += 256)
        atomicAdd(&h[dst[e] >> NBITS], 1);
    __syncthreads();
    for (int i = tid; i < NB; i += 256) if (h[i]) atomicAdd(&bhist[i], h[i]);
}

__global__ void bucket_scan_kernel(const int* __restrict__ bhist, int* __restrict__ bstart,
                                   int* __restrict__ bcur, int* __restrict__ offs,
                                   int n, int E) {
    __shared__ int cw[2];
    int tid = threadIdx.x, lane = tid & 63, w = tid >> 6;
    int v = bhist[tid], xv = v;
#pragma unroll
    for (int d = 1; d < 64; d <<= 1) {
        int t = __shfl_up(xv, d, 64);
        if (lane >= d) xv += t;
    }
    if (lane == 63) cw[w] = xv;
    __syncthreads();
    int excl = xv - v + ((w == 1) ? cw[0] : 0);
    bstart[tid] = excl;
    bcur[tid] = excl;
    if (tid == 127) bstart[128] = excl + v;
    if (tid == 0) offs[n] = E + n;
}

__global__ void scatter_kernel(const int* __restrict__ src, const int* __restrict__ dst,
                               int* __restrict__ bcur, unsigned int* __restrict__ bents, int E) {
    __shared__ int hist[NB];
    __shared__ int binoff[NB];
    __shared__ int runbase[NB];
    __shared__ unsigned int ebuf[EPB];
    __shared__ unsigned short binOf[EPB];
    __shared__ int cw[2];
    int tid = threadIdx.x, lane = tid & 63, w = tid >> 6;
    int base = blockIdx.x * EPB;
    int cnt = min(EPB, E - base);
    for (int i = tid; i < NB; i += 256) hist[i] = 0;
    __syncthreads();
    unsigned int pk[32];
    int rk[32];
#pragma unroll
    for (int j = 0; j < 32; ++j) {
        int idx = tid + 256 * j;
        if (idx < cnt) {
            int e = base + idx;
            int s = src[e], d = dst[e];
            pk[j] = (unsigned int)s | ((unsigned int)d << 16);
            int bin = d >> NBITS;
            int r = atomicAdd(&hist[bin], 1);
            rk[j] = r | (bin << 16);
        } else rk[j] = -1;
    }
    __syncthreads();
    int v = 0, xv = 0;
    if (tid < NB) {
        v = hist[tid]; xv = v;
#pragma unroll
        for (int d = 1; d < 64; d <<= 1) {
            int t = __shfl_up(xv, d, 64);
            if (lane >= d) xv += t;
        }
        if (lane == 63) cw[w] = xv;
    }
    __syncthreads();
    if (tid < NB) {
        binoff[tid] = xv - v + ((w == 1) ? cw[0] : 0);
        runbase[tid] = v ? atomicAdd(&bcur[tid], v) : 0;
    }
    __syncthreads();
#pragma unroll
    for (int j = 0; j < 32; ++j) {
        if (rk[j] >= 0) {
            int bin = rk[j] >> 16, r = rk[j] & 0xFFFF;
            int pos = binoff[bin] + r;
            ebuf[pos] = pk[j];
            binOf[pos] = (unsigned short)bin;
        }
    }
    __syncthreads();
    for (int i = tid; i < cnt; i += 256) {
        int bin = binOf[i];
        bents[runbase[bin] + (i - binoff[bin])] = ebuf[i];
    }
}

__global__ void build_kernel(const unsigned int* __restrict__ bents, const int* __restrict__ bstart,
                             const float* __restrict__ x, const int* __restrict__ batch,
                             int* __restrict__ offs, unsigned short* __restrict__ csr16,
                             float* __restrict__ dinv, float* __restrict__ gcnt,
                             float* __restrict__ x16, int n) {
    __shared__ int counts[RNODES];
    __shared__ int lcur[RNODES];
    __shared__ unsigned short outl[13824];
    __shared__ int wsums[8];
    int tid = threadIdx.x;          // 1024
    int lane = tid & 63, w = tid >> 6;
    int b = blockIdx.x;
    int base = b << NBITS;
    int nn = min(RNODES, n - base);
    int ebase = bstart[b], ecnt = bstart[b + 1] - ebase;
    for (int i = tid; i < RNODES; i += 1024) counts[i] = 0;
    __syncthreads();
    for (int e = tid; e < ecnt; e += 1024)
        atomicAdd(&counts[(bents[ebase + e] >> 16) - base], 1);
    __syncthreads();
    int v = 0, xv = 0;
    if (tid < RNODES) {
        v = (tid < nn) ? counts[tid] + 1 : 0;
        xv = v;
#pragma unroll
        for (int d = 1; d < 64; d <<= 1) {
            int t = __shfl_up(xv, d, 64);
            if (lane >= d) xv += t;
        }
        if (lane == 63) wsums[w] = xv;
    }
    __syncthreads();
    if (tid < 64) {
        int s = (lane < 8) ? wsums[lane] : 0;
#pragma unroll
        for (int d = 1; d < 8; d <<= 1) {
            int t = __shfl_up(s, d, 64);
            if (lane >= d) s += t;
        }
        if (lane < 8) wsums[lane] = s;
    }
    __syncthreads();
    if (tid < nn) {
        int excl = xv - v + ((w > 0) ? wsums[w - 1] : 0);
        lcur[tid] = excl + 1;
        outl[excl] = (unsigned short)(base + tid);        // self-loop slot 0
        offs[base + tid] = ebase + base + excl;
        atomicAdd(&gcnt[batch[base + tid]], 1.0f);
    }
    __syncthreads();
    for (int e = tid; e < ecnt; e += 1024) {
        unsigned int pk = bents[ebase + e];
        int i = (int)(pk >> 16) - base;
        int r = atomicAdd(&lcur[i], 1);
        outl[r] = (unsigned short)(pk & 0xFFFFu);
    }
    __syncthreads();
    int total = ecnt + nn;
    for (int i = tid; i < total; i += 1024)
        csr16[ebase + base + i] = outl[i];
    for (int idx = tid; idx < nn * 16; idx += 1024) {
        int i = idx >> 4, j = idx & 15;
        float di = 1.0f / sqrtf((float)(counts[i] + 1));
        if (j == 0) dinv[base + i] = di;
        x16[(long)(base + i) * 16 + j] = (j < F_IN) ? x[(long)(base + i) * F_IN + j] * di : 0.f;
    }
}

// ---------------- layer 1 ----------------

__global__ void agg16_kernel(const float* __restrict__ xs, const int* __restrict__ offs,
                             const unsigned short* __restrict__ csr16, const float* __restrict__ dinv,
                             float* __restrict__ z16, int n) {
    int node = (int)(((long)blockIdx.x * blockDim.x + threadIdx.x) >> 6);
    int lane = threadIdx.x & 63;
    if (node >= n) return;
    int grp = lane >> 4, f = lane & 15;
    int beg = offs[node], end = offs[node + 1];
    float acc = 0.f;
    int eb = beg;
    for (; eb + 16 <= end; eb += 16) {
        int s[4]; float v[4];
#pragma unroll
        for (int j = 0; j < 4; ++j) s[j] = csr16[eb + grp + 4 * j];
#pragma unroll
        for (int j = 0; j < 4; ++j) v[j] = xs[(long)s[j] * 16 + f];
#pragma unroll
        for (int j = 0; j < 4; ++j) acc += v[j];
    }
    if (eb + 8 <= end) {
        int s0 = csr16[eb + grp], s1 = csr16[eb + grp + 4];
        acc += xs[(long)s0 * 16 + f] + xs[(long)s1 * 16 + f];
        eb += 8;
    }
    for (int e = eb + grp; e < end; e += 4)
        acc += xs[(long)csr16[e] * 16 + f];
    acc += __shfl_down(acc, 32);
    acc += __shfl_down(acc, 16);
    if (lane < 16) z16[(long)node * 16 + lane] = acc * dinv[node];
}

// h1 = relu(z16[:, :11] @ W1 + b1) -> fp16; 8 nodes per 256-thread block
__global__ void gemm_in_kernel(const float* __restrict__ z16, const float* __restrict__ W1,
                               const float* __restrict__ b1, __half* __restrict__ out, int n) {
    __shared__ float Ws[F_IN * HIDDEN];
    __shared__ float bs[HIDDEN];
    __shared__ float zs[8][16];
    int tid = threadIdx.x;
    long base = (long)blockIdx.x * 8;
    for (int i = tid; i < F_IN * HIDDEN; i += 256) Ws[i] = W1[i];
    if (tid < HIDDEN) bs[tid] = b1[tid];
    if (tid < 128) {
        int ln = tid >> 4, f = tid & 15;
        long gn = base + ln;
        zs[ln][f] = (gn < n) ? z16[gn * 16 + f] : 0.f;
    }
    __syncthreads();
    int f = tid & 127, half_ = tid >> 7;
#pragma unroll
    for (int r = 0; r < 4; ++r) {
        int ln = half_ * 4 + r;
        long gn = base + ln;
        float acc = bs[f];
#pragma unroll
        for (int k = 0; k < F_IN; ++k) acc += zs[ln][k] * Ws[k * HIDDEN + f];
        if (gn < n) out[gn * HIDDEN + f] = __float2half(fmaxf(acc, 0.f));
    }
}

// ---------------- layer-2 GEMM: MFMA f16, ROW-major fp16 output ----------------
// 64 nodes/block, 4 waves x 16 nodes; A from global (h1 fp16 rows), W2T in LDS.

__global__ __launch_bounds__(256) void gemm_mfma_kernel(
        const __half* __restrict__ h1h, const float* __restrict__ W2,
        const float* __restrict__ dinv, __half* __restrict__ hsh, int n) {
    __shared__ _Float16 W2T[128 * 136];    // [n][k], stride 136
    __shared__ _Float16 outs[64 * 136];    // [node][feat], stride 136 (16B-aligned rows)
    int tid = threadIdx.x;
    for (int i = tid; i < 128 * 128; i += 256) {
        int k = i >> 7, nn = i & 127;
        W2T[nn * 136 + k] = (_Float16)W2[i];
    }
    int base = blockIdx.x * 64;
    int lane = tid & 63, wid = tid >> 6;
    int l15 = lane & 15, quad = lane >> 4;
    int arow = base + wid * 16 + l15;
    if (arow >= n) arow = n - 1;           // clamp: safe reads, invalid rows unwritten
    const _Float16* Aptr = (const _Float16*)h1h + (size_t)arow * 128;
    floatx4 acc[8];
#pragma unroll
    for (int t = 0; t < 8; ++t) acc[t] = (floatx4){0.f, 0.f, 0.f, 0.f};
    __syncthreads();
#pragma unroll
    for (int c = 0; c < 4; ++c) {
        half8 a = *(const half8*)(Aptr + c * 32 + quad * 8);
#pragma unroll
        for (int t = 0; t < 8; ++t) {
            half8 b = *(const half8*)(&W2T[(t * 16 + l15) * 136 + c * 32 + quad * 8]);
            acc[t] = __builtin_amdgcn_mfma_f32_16x16x32_f16(a, b, acc[t], 0, 0, 0);
        }
    }
    // D layout: row(m)=quad*4+reg, col(n)=l15
    float dv[4];
#pragma unroll
    for (int r = 0; r < 4; ++r) {
        int nd = base + wid * 16 + quad * 4 + r;
        dv[r] = dinv[(nd < n) ? nd : 0];
    }
#pragma unroll
    for (int t = 0; t < 8; ++t)
#pragma unroll
        for (int r = 0; r < 4; ++r)
            outs[(wid * 16 + quad * 4 + r) * 136 + t * 16 + l15] = (_Float16)(acc[t][r] * dv[r]);
    __syncthreads();
    // row-major copy out: 64 rows x 16 uint4 (128 halves) each
    for (int i = tid; i < 64 * 16; i += 256) {
        int ln = i >> 4, qq = i & 15;
        long nd = base + ln;
        if (nd < n) {
            uint4 u = *(uint4*)&outs[ln * 136 + qq * 8];
            ((uint4*)hsh)[nd * 16 + qq] = u;
        }
    }
}

// ---------------- 128-wide agg (layer 2): half in, fp32 out (R7 proven) ----------------

__global__ void agg128h_kernel(const __half* __restrict__ hsh, const int* __restrict__ offs,
                               const unsigned short* __restrict__ csr16, const float* __restrict__ dinv,
                               const float* __restrict__ bias, float* __restrict__ out, int n) {
    int node = (int)(((long)blockIdx.x * blockDim.x + threadIdx.x) >> 6);
    int lane = threadIdx.x & 63;
    if (node >= n) return;
    int grp = lane >> 5, q = lane & 31;
    int beg = offs[node], end = offs[node + 1];
    float4 acc = make_float4(0.f, 0.f, 0.f, 0.f);
    int eb = beg;
    for (; eb + 16 <= end; eb += 16) {
        int s[8]; uint2 u[8];
#pragma unroll
        for (int j = 0; j < 8; ++j) s[j] = csr16[eb + grp + 2 * j];
#pragma unroll
        for (int j = 0; j < 8; ++j) u[j] = ((const uint2*)hsh)[(long)s[j] * 32 + q];
#pragma unroll
        for (int j = 0; j < 8; ++j) {
            float2 lo = __half22float2(*(__half2*)&u[j].x);
            float2 hi = __half22float2(*(__half2*)&u[j].y);
            acc.x += lo.x; acc.y += lo.y; acc.z += hi.x; acc.w += hi.y;
        }
    }
    if (eb + 8 <= end) {
        int s[4]; uint2 u[4];
#pragma unroll
        for (int j = 0; j < 4; ++j) s[j] = csr16[eb + grp + 2 * j];
#pragma unroll
        for (int j = 0; j < 4; ++j) u[j] = ((const uint2*)hsh)[(long)s[j] * 32 + q];
#pragma unroll
        for (int j = 0; j < 4; ++j) {
            float2 lo = __half22float2(*(__half2*)&u[j].x);
            float2 hi = __half22float2(*(__half2*)&u[j].y);
            acc.x += lo.x; acc.y += lo.y; acc.z += hi.x; acc.w += hi.y;
        }
        eb += 8;
    }
    for (int e = eb + grp; e < end; e += 2) {
        uint2 u = ((const uint2*)hsh)[(long)csr16[e] * 32 + q];
        float2 lo = __half22float2(*(__half2*)&u.x);
        float2 hi = __half22float2(*(__half2*)&u.y);
        acc.x += lo.x; acc.y += lo.y; acc.z += hi.x; acc.w += hi.y;
    }
    acc.x += __shfl_down(acc.x, 32);
    acc.y += __shfl_down(acc.y, 32);
    acc.z += __shfl_down(acc.z, 32);
    acc.w += __shfl_down(acc.w, 32);
    if (grp == 0) {
        float di = dinv[node];
        float4 b = ((const float4*)bias)[q];
        acc.x = fmaxf(acc.x * di + b.x, 0.f);
        acc.y = fmaxf(acc.y * di + b.y, 0.f);
        acc.z = fmaxf(acc.z * di + b.z, 0.f);
        acc.w = fmaxf(acc.w * di + b.w, 0.f);
        ((float4*)(out + (long)node * HIDDEN))[q] = acc;
    }
}

// ---------------- folded layer 3 + pool + head ----------------

__global__ void w3l_kernel(const float* __restrict__ W3, const float* __restrict__ Wl,
                           const float* __restrict__ b3, float* __restrict__ W3l,
                           float* __restrict__ b3l) {
    __shared__ float Wls[HIDDEN * NCLS];
    int tid = threadIdx.x;
    for (int i = tid; i < HIDDEN * NCLS; i += 256) Wls[i] = Wl[i];
    __syncthreads();
    if (blockIdx.x < 10) {
        int o = blockIdx.x * 256 + tid;
        if (o < HIDDEN * NCLS) {
            int i = o / NCLS, j = o % NCLS;
            float acc = 0.f;
#pragma unroll 8
            for (int k = 0; k < HIDDEN; ++k) acc += W3[i * HIDDEN + k] * Wls[k * NCLS + j];
            W3l[o] = acc;
        }
    } else if (tid < NCLS) {
        float acc = 0.f;
#pragma unroll 8
        for (int k = 0; k < HIDDEN; ++k) acc += b3[k] * Wls[k * NCLS + tid];
        b3l[tid] = acc;
    }
}

__global__ void gemm_y32h_kernel(const float* __restrict__ h2, const float* __restrict__ W3l,
                                 const float* __restrict__ dinv, __half* __restrict__ ys, int n) {
    __shared__ float hs[12][HIDDEN];
    __shared__ float Ws[HIDDEN][20];
    int tid = threadIdx.x;
    long base = (long)blockIdx.x * 12;
    for (int i = tid; i < HIDDEN * NCLS; i += 256) Ws[i / NCLS][i % NCLS] = W3l[i];
    for (int idx = tid; idx < 12 * 32; idx += 256) {
        int node = idx >> 5, q = idx & 31;
        long gn = base + node;
        float4 a = (gn < n) ? ((const float4*)(h2 + gn * HIDDEN))[q]
                            : make_float4(0.f, 0.f, 0.f, 0.f);
        *(float4*)&hs[node][q * 4] = a;
    }
    __syncthreads();
    if (tid < 12 * NCLS) {
        int node = tid / NCLS, j = tid % NCLS;
        long gn = base + node;
        if (gn < n) {
            float acc = 0.f;
#pragma unroll 8
            for (int k = 0; k < HIDDEN; ++k) acc += hs[node][k] * Ws[k][j];
            ys[gn * 32 + j] = __float2half(acc * dinv[gn]);
        }
    }
    for (int idx = tid; idx < 12 * 13; idx += 256) {
        int node = idx / 13, j = 19 + idx % 13;
        long gn = base + node;
        if (gn < n) ys[gn * 32 + j] = __half(0.f);
    }
}

__global__ void agg24h_pool_kernel(const __half* __restrict__ ys, const int* __restrict__ offs,
                                   const unsigned short* __restrict__ csr16, const float* __restrict__ dinv,
                                   const int* __restrict__ batch, float* __restrict__ pool, int n) {
    int node = (int)(((long)blockIdx.x * blockDim.x + threadIdx.x) >> 6);
    int lane = threadIdx.x & 63;
    if (node >= n) return;
    int grp = lane >> 4, f = lane & 15;
    int beg = offs[node], end = offs[node + 1];
    float2 acc = {0.f, 0.f};
    int eb = beg;
    for (; eb + 32 <= end; eb += 32) {
        int s[8]; unsigned int u[8];
#pragma unroll
        for (int j = 0; j < 8; ++j) s[j] = csr16[eb + grp + 4 * j];
#pragma unroll
        for (int j = 0; j < 8; ++j) u[j] = ((const unsigned int*)ys)[(long)s[j] * 16 + f];
#pragma unroll
        for (int j = 0; j < 8; ++j) {
            float2 v = __half22float2(*(__half2*)&u[j]);
            acc.x += v.x; acc.y += v.y;
        }
    }
    if (eb + 16 <= end) {
        int s[4]; unsigned int u[4];
#pragma unroll
        for (int j = 0; j < 4; ++j) s[j] = csr16[eb + grp + 4 * j];
#pragma unroll
        for (int j = 0; j < 4; ++j) u[j] = ((const unsigned int*)ys)[(long)s[j] * 16 + f];
#pragma unroll
        for (int j = 0; j < 4; ++j) {
            float2 v = __half22float2(*(__half2*)&u[j]);
            acc.x += v.x; acc.y += v.y;
        }
        eb += 16;
    }
    for (int e = eb + grp; e < end; e += 4) {
        unsigned int u = ((const unsigned int*)ys)[(long)csr16[e] * 16 + f];
        float2 v = __half22float2(*(__half2*)&u);
        acc.x += v.x; acc.y += v.y;
    }
    acc.x += __shfl_down(acc.x, 32);
    acc.y += __shfl_down(acc.y, 32);
    acc.x += __shfl_down(acc.x, 16);
    acc.y += __shfl_down(acc.y, 16);
    if (lane < 16) {
        int g = batch[node];
        float sc = dinv[node];
        int c0 = 2 * f;
        if (c0 < NCLS) atomicAdd(&pool[(long)g * 24 + c0], acc.x * sc);
        if (c0 + 1 < NCLS) atomicAdd(&pool[(long)g * 24 + c0 + 1], acc.y * sc);
    }
}

__global__ void final_kernel(const float* __restrict__ pool, const float* __restrict__ cnt,
                             const float* __restrict__ b3l, const float* __restrict__ bl,
                             float* __restrict__ out, int G) {
    int i = blockIdx.x * blockDim.x + threadIdx.x;
    if (i >= G * NCLS) return;
    int g = i / NCLS, j = i % NCLS;
    float c = cnt[g];
    out[i] = (c > 0.f) ? pool[(long)g * 24 + j] / c + b3l[j] + bl[j] : bl[j];
}

// ---------------- launch ----------------

static inline size_t align256(size_t x) { return (x + 255) & ~(size_t)255; }

extern "C" void kernel_launch(void* const* d_in, const int* in_sizes, int n_in,
                              void* d_out, int out_size, void* d_ws, size_t ws_size,
                              hipStream_t stream) {
    const float* x    = (const float*)d_in[0];
    const int*   ei   = (const int*)d_in[1];
    const int*   batch= (const int*)d_in[2];
    const float* W1   = (const float*)d_in[3];
    const float* b1   = (const float*)d_in[4];
    const float* W2   = (const float*)d_in[5];
    const float* b2   = (const float*)d_in[6];
    const float* W3   = (const float*)d_in[7];
    const float* b3   = (const float*)d_in[8];
    const float* Wl   = (const float*)d_in[9];
    const float* bl   = (const float*)d_in[10];
    float* out = (float*)d_out;

    const int N = in_sizes[0] / F_IN;
    const int E = in_sizes[1] / 2;
    const int G = out_size / NCLS;
    const int* src = ei;
    const int* dst = ei + E;
    const int nSB = (E + EPB - 1) / EPB;
    const int nBK = (N + RNODES - 1) / RNODES;

    // workspace carve-up
    char* p = (char*)d_ws;
    size_t off = 0;
    int*            bhist  = (int*)(p + off);            off = align256(off + NB * 4);
    int*            bstart = (int*)(p + off);            off = align256(off + (NB + 1) * 4);
    int*            bcur   = (int*)(p + off);            off = align256(off + NB * 4);
    unsigned int*   bents  = (unsigned int*)(p + off);   off = align256(off + (size_t)E * 4);
    unsigned short* csr16  = (unsigned short*)(p + off); off = align256(off + (size_t)(E + N) * 2);
    int*            offs   = (int*)(p + off);            off = align256(off + (size_t)(N + 1) * 4);
    float*          dinv   = (float*)(p + off);          off = align256(off + (size_t)N * 4);
    float*          x16    = (float*)(p + off);          off = align256(off + (size_t)N * 16 * 4);
    float*          z16    = (float*)(p + off);          off = align256(off + (size_t)N * 16 * 4);
    __half*         h1h    = (__half*)(p + off);         off = align256(off + (size_t)N * HIDDEN * 2);
    __half*         hsh    = (__half*)(p + off);         off = align256(off + (size_t)N * HIDDEN * 2);
    __half*         y32h   = (__half*)(p + off);         off = align256(off + (size_t)N * 32 * 2);
    float*          W3l    = (float*)(p + off);          off = align256(off + (size_t)HIDDEN * NCLS * 4);
    float*          b3l    = (float*)(p + off);          off = align256(off + (size_t)NCLS * 4);
    float*          pool   = (float*)(p + off);          off = align256(off + (size_t)G * 25 * 4);
    float*          gcnt   = pool + (size_t)G * 24;
    float*          h_a    = (float*)(p + off);          off = align256(off + (size_t)N * HIDDEN * 4);
    (void)ws_size; (void)n_in;

    hipMemsetAsync(bhist, 0, NB * 4, stream);
    hipMemsetAsync(pool, 0, (size_t)G * 25 * 4, stream);

    // bucketed CSR build
    hist_kernel<<<nSB, 256, 0, stream>>>(dst, bhist, E);
    bucket_scan_kernel<<<1, 128, 0, stream>>>(bhist, bstart, bcur, offs, N, E);
    scatter_kernel<<<nSB, 256, 0, stream>>>(src, dst, bcur, bents, E);
    build_kernel<<<nBK, 1024, 0, stream>>>(bents, bstart, x, batch, offs, csr16,
                                           dinv, gcnt, x16, N);
    w3l_kernel<<<11, 256, 0, stream>>>(W3, Wl, b3, W3l, b3l);

    const int aggBlocks = (N + 3) / 4;  // 4 waves/block, wave per node

    // layer 1: z16 = dinv * sum(x16) ; h1 = relu(z16@W1+b1) -> fp16
    agg16_kernel<<<aggBlocks, 256, 0, stream>>>(x16, offs, csr16, dinv, z16, N);
    gemm_in_kernel<<<(N + 7) / 8, 256, 0, stream>>>(z16, W1, b1, h1h, N);

    // layer 2: hsh = half((h1@W2)*dinv) row-major [MFMA] ; h2 = relu(dinv*sum + b2)
    gemm_mfma_kernel<<<(N + 63) / 64, 256, 0, stream>>>(h1h, W2, dinv, hsh, N);
    agg128h_kernel<<<aggBlocks, 256, 0, stream>>>(hsh, offs, csr16, dinv, b2, h_a, N);

    // folded layer 3 + pool
    gemm_y32h_kernel<<<(N + 11) / 12, 256, 0, stream>>>(h_a, W3l, dinv, y32h, N);
    agg24h_pool_kernel<<<aggBlocks, 256, 0, stream>>>(y32h, offs, csr16, dinv, batch, pool, N);
    final_kernel<<<(G * NCLS + 255) / 256, 256, 0, stream>>>(pool, gcnt, b3l, bl, out, G);
}

// Round 11
// 252.474 us; speedup vs baseline: 1.2947x; 1.0491x over previous
//
#include <hip/hip_runtime.h>
#include <hip/hip_bf16.h>
#include <hip/hip_fp16.h>

// GCN2: 3x GCNConv(relu,relu,none) + global_mean_pool + linear head.
// R11 = R10 with the bucket-capacity bug fixed. R10 sized cap by E/128,
// but only ~N/512=97.7 of 128 buckets are populated -> mean 8192 edges per
// used bucket > 8068 cap -> overflow -> LDS corruption -> NaN. Now
// cap = E*512/N + 1024 (~11 sigma) AND hard clamps in scatter/build so
// overflow can only drop edges, never corrupt.

#define HIDDEN 128
#define F_IN 11
#define NCLS 19
#define NBITS 9
#define NB 128
#define RNODES 512
#define EPB 8192
#define OUTL_CAP 10240

typedef _Float16 half8 __attribute__((ext_vector_type(8)));
typedef float floatx4 __attribute__((ext_vector_type(4)));

// ---------------- bucketed CSR build (2 kernels) ----------------

// per block: 8192 edges -> LDS bucket-sorted -> append runs to padded bucket regions
__global__ void scatter_kernel(const int* __restrict__ src, const int* __restrict__ dst,
                               int* __restrict__ bcur, unsigned int* __restrict__ bents,
                               int E, int cap) {
    __shared__ int hist[NB];
    __shared__ int binoff[NB];
    __shared__ int runrel[NB];
    __shared__ unsigned int ebuf[EPB];
    __shared__ unsigned short binOf[EPB];
    __shared__ int cw[2];
    int tid = threadIdx.x, lane = tid & 63, w = tid >> 6;
    int base = blockIdx.x * EPB;
    int cnt = min(EPB, E - base);
    for (int i = tid; i < NB; i += 256) hist[i] = 0;
    __syncthreads();
    unsigned int pk[32];
    int rk[32];
#pragma unroll
    for (int j = 0; j < 32; ++j) {
        int idx = tid + 256 * j;
        if (idx < cnt) {
            int e = base + idx;
            int s = src[e], d = dst[e];
            pk[j] = (unsigned int)s | ((unsigned int)d << 16);
            int bin = d >> NBITS;
            int r = atomicAdd(&hist[bin], 1);
            rk[j] = r | (bin << 16);
        } else rk[j] = -1;
    }
    __syncthreads();
    int v = 0, xv = 0;
    if (tid < NB) {
        v = hist[tid]; xv = v;
#pragma unroll
        for (int d = 1; d < 64; d <<= 1) {
            int t = __shfl_up(xv, d, 64);
            if (lane >= d) xv += t;
        }
        if (lane == 63) cw[w] = xv;
    }
    __syncthreads();
    if (tid < NB) {
        binoff[tid] = xv - v + ((w == 1) ? cw[0] : 0);
        runrel[tid] = v ? atomicAdd(&bcur[tid], v) : 0;
    }
    __syncthreads();
#pragma unroll
    for (int j = 0; j < 32; ++j) {
        if (rk[j] >= 0) {
            int bin = rk[j] >> 16, r = rk[j] & 0xFFFF;
            int pos = binoff[bin] + r;
            ebuf[pos] = pk[j];
            binOf[pos] = (unsigned short)bin;
        }
    }
    __syncthreads();
    for (int i = tid; i < cnt; i += 256) {
        int bin = binOf[i];
        int rel = runrel[bin] + (i - binoff[bin]);
        if (rel < cap)                          // hard guard: never cross regions
            bents[bin * cap + rel] = ebuf[i];
    }
}

// per bucket: counts -> scan -> LDS scatter (self + srcs) -> dense writes.
__global__ void build_kernel(const unsigned int* __restrict__ bents, const int* __restrict__ bcur,
                             const float* __restrict__ x, const int* __restrict__ batch,
                             int2* __restrict__ begend, unsigned short* __restrict__ csr16,
                             float* __restrict__ dinv, float* __restrict__ gcnt,
                             float* __restrict__ x16, int n, int cap, int rst) {
    __shared__ int counts[RNODES];
    __shared__ int lcur[RNODES];
    __shared__ unsigned short outl[OUTL_CAP];
    __shared__ int wsums[8];
    int tid = threadIdx.x;          // 1024
    int lane = tid & 63, w = tid >> 6;
    int b = blockIdx.x;
    int base = b << NBITS;
    int nn = min(RNODES, n - base);
    int ebase = b * cap;
    int ecnt = min(bcur[b], cap);   // hard guard
    int st = b * rst;
    for (int i = tid; i < RNODES; i += 1024) counts[i] = 0;
    __syncthreads();
    for (int e = tid; e < ecnt; e += 1024)
        atomicAdd(&counts[(bents[ebase + e] >> 16) - base], 1);
    __syncthreads();
    int v = 0, xv = 0;
    if (tid < RNODES) {
        v = (tid < nn) ? counts[tid] + 1 : 0;
        xv = v;
#pragma unroll
        for (int d = 1; d < 64; d <<= 1) {
            int t = __shfl_up(xv, d, 64);
            if (lane >= d) xv += t;
        }
        if (lane == 63) wsums[w] = xv;
    }
    __syncthreads();
    if (tid < 64) {
        int s = (lane < 8) ? wsums[lane] : 0;
#pragma unroll
        for (int d = 1; d < 8; d <<= 1) {
            int t = __shfl_up(s, d, 64);
            if (lane >= d) s += t;
        }
        if (lane < 8) wsums[lane] = s;
    }
    __syncthreads();
    if (tid < nn) {
        int excl = xv - v + ((w > 0) ? wsums[w - 1] : 0);
        lcur[tid] = excl + 1;
        outl[excl] = (unsigned short)(base + tid);        // self-loop slot 0
        begend[base + tid] = make_int2(st + excl, st + excl + v);
        atomicAdd(&gcnt[batch[base + tid]], 1.0f);
    }
    __syncthreads();
    for (int e = tid; e < ecnt; e += 1024) {
        unsigned int pk = bents[ebase + e];
        int i = (int)(pk >> 16) - base;
        int r = atomicAdd(&lcur[i], 1);
        outl[r] = (unsigned short)(pk & 0xFFFFu);
    }
    __syncthreads();
    int total = ecnt + nn;
    for (int i = tid; i < total; i += 1024)
        csr16[st + i] = outl[i];
    for (int idx = tid; idx < nn * 16; idx += 1024) {
        int i = idx >> 4, j = idx & 15;
        float di = 1.0f / sqrtf((float)(counts[i] + 1));
        if (j == 0) dinv[base + i] = di;
        x16[(long)(base + i) * 16 + j] = (j < F_IN) ? x[(long)(base + i) * F_IN + j] * di : 0.f;
    }
}

// ---------------- layer 1 ----------------

__global__ void agg16_kernel(const float* __restrict__ xs, const int2* __restrict__ begend,
                             const unsigned short* __restrict__ csr16, const float* __restrict__ dinv,
                             float* __restrict__ z16, int n) {
    int node = (int)(((long)blockIdx.x * blockDim.x + threadIdx.x) >> 6);
    int lane = threadIdx.x & 63;
    if (node >= n) return;
    int grp = lane >> 4, f = lane & 15;
    int2 be = begend[node];
    int beg = be.x, end = be.y;
    float acc = 0.f;
    int eb = beg;
    for (; eb + 16 <= end; eb += 16) {
        int s[4]; float v[4];
#pragma unroll
        for (int j = 0; j < 4; ++j) s[j] = csr16[eb + grp + 4 * j];
#pragma unroll
        for (int j = 0; j < 4; ++j) v[j] = xs[(long)s[j] * 16 + f];
#pragma unroll
        for (int j = 0; j < 4; ++j) acc += v[j];
    }
    if (eb + 8 <= end) {
        int s0 = csr16[eb + grp], s1 = csr16[eb + grp + 4];
        acc += xs[(long)s0 * 16 + f] + xs[(long)s1 * 16 + f];
        eb += 8;
    }
    for (int e = eb + grp; e < end; e += 4)
        acc += xs[(long)csr16[e] * 16 + f];
    acc += __shfl_down(acc, 32);
    acc += __shfl_down(acc, 16);
    if (lane < 16) z16[(long)node * 16 + lane] = acc * dinv[node];
}

// h1 = relu(z16[:, :11] @ W1 + b1) -> fp16; 8 nodes per 256-thread block
__global__ void gemm_in_kernel(const float* __restrict__ z16, const float* __restrict__ W1,
                               const float* __restrict__ b1, __half* __restrict__ out, int n) {
    __shared__ float Ws[F_IN * HIDDEN];
    __shared__ float bs[HIDDEN];
    __shared__ float zs[8][16];
    int tid = threadIdx.x;
    long base = (long)blockIdx.x * 8;
    for (int i = tid; i < F_IN * HIDDEN; i += 256) Ws[i] = W1[i];
    if (tid < HIDDEN) bs[tid] = b1[tid];
    if (tid < 128) {
        int ln = tid >> 4, f = tid & 15;
        long gn = base + ln;
        zs[ln][f] = (gn < n) ? z16[gn * 16 + f] : 0.f;
    }
    __syncthreads();
    int f = tid & 127, half_ = tid >> 7;
#pragma unroll
    for (int r = 0; r < 4; ++r) {
        int ln = half_ * 4 + r;
        long gn = base + ln;
        float acc = bs[f];
#pragma unroll
        for (int k = 0; k < F_IN; ++k) acc += zs[ln][k] * Ws[k * HIDDEN + f];
        if (gn < n) out[gn * HIDDEN + f] = __float2half(fmaxf(acc, 0.f));
    }
}

// ---------------- layer-2 GEMM: MFMA f16, ROW-major fp16 output ----------------

__global__ __launch_bounds__(256) void gemm_mfma_kernel(
        const __half* __restrict__ h1h, const float* __restrict__ W2,
        const float* __restrict__ dinv, __half* __restrict__ hsh, int n) {
    __shared__ _Float16 W2T[128 * 136];    // [n][k], stride 136
    __shared__ _Float16 outs[64 * 136];    // [node][feat], stride 136
    int tid = threadIdx.x;
    for (int i = tid; i < 128 * 128; i += 256) {
        int k = i >> 7, nn = i & 127;
        W2T[nn * 136 + k] = (_Float16)W2[i];
    }
    int base = blockIdx.x * 64;
    int lane = tid & 63, wid = tid >> 6;
    int l15 = lane & 15, quad = lane >> 4;
    int arow = base + wid * 16 + l15;
    if (arow >= n) arow = n - 1;           // clamp: safe reads, invalid rows unwritten
    const _Float16* Aptr = (const _Float16*)h1h + (size_t)arow * 128;
    floatx4 acc[8];
#pragma unroll
    for (int t = 0; t < 8; ++t) acc[t] = (floatx4){0.f, 0.f, 0.f, 0.f};
    __syncthreads();
#pragma unroll
    for (int c = 0; c < 4; ++c) {
        half8 a = *(const half8*)(Aptr + c * 32 + quad * 8);
#pragma unroll
        for (int t = 0; t < 8; ++t) {
            half8 b = *(const half8*)(&W2T[(t * 16 + l15) * 136 + c * 32 + quad * 8]);
            acc[t] = __builtin_amdgcn_mfma_f32_16x16x32_f16(a, b, acc[t], 0, 0, 0);
        }
    }
    float dv[4];
#pragma unroll
    for (int r = 0; r < 4; ++r) {
        int nd = base + wid * 16 + quad * 4 + r;
        dv[r] = dinv[(nd < n) ? nd : 0];
    }
#pragma unroll
    for (int t = 0; t < 8; ++t)
#pragma unroll
        for (int r = 0; r < 4; ++r)
            outs[(wid * 16 + quad * 4 + r) * 136 + t * 16 + l15] = (_Float16)(acc[t][r] * dv[r]);
    __syncthreads();
    for (int i = tid; i < 64 * 16; i += 256) {
        int ln = i >> 4, qq = i & 15;
        long nd = base + ln;
        if (nd < n) {
            uint4 u = *(uint4*)&outs[ln * 136 + qq * 8];
            ((uint4*)hsh)[nd * 16 + qq] = u;
        }
    }
}

// ---------------- 128-wide agg (layer 2): half in, half out ----------------

__global__ void agg128h_kernel(const __half* __restrict__ hsh, const int2* __restrict__ begend,
                               const unsigned short* __restrict__ csr16, const float* __restrict__ dinv,
                               const float* __restrict__ bias, __half* __restrict__ outh, int n) {
    int node = (int)(((long)blockIdx.x * blockDim.x + threadIdx.x) >> 6);
    int lane = threadIdx.x & 63;
    if (node >= n) return;
    int grp = lane >> 5, q = lane & 31;
    int2 be = begend[node];
    int beg = be.x, end = be.y;
    float4 acc = make_float4(0.f, 0.f, 0.f, 0.f);
    int eb = beg;
    for (; eb + 16 <= end; eb += 16) {
        int s[8]; uint2 u[8];
#pragma unroll
        for (int j = 0; j < 8; ++j) s[j] = csr16[eb + grp + 2 * j];
#pragma unroll
        for (int j = 0; j < 8; ++j) u[j] = ((const uint2*)hsh)[(long)s[j] * 32 + q];
#pragma unroll
        for (int j = 0; j < 8; ++j) {
            float2 lo = __half22float2(*(__half2*)&u[j].x);
            float2 hi = __half22float2(*(__half2*)&u[j].y);
            acc.x += lo.x; acc.y += lo.y; acc.z += hi.x; acc.w += hi.y;
        }
    }
    if (eb + 8 <= end) {
        int s[4]; uint2 u[4];
#pragma unroll
        for (int j = 0; j < 4; ++j) s[j] = csr16[eb + grp + 2 * j];
#pragma unroll
        for (int j = 0; j < 4; ++j) u[j] = ((const uint2*)hsh)[(long)s[j] * 32 + q];
#pragma unroll
        for (int j = 0; j < 4; ++j) {
            float2 lo = __half22float2(*(__half2*)&u[j].x);
            float2 hi = __half22float2(*(__half2*)&u[j].y);
            acc.x += lo.x; acc.y += lo.y; acc.z += hi.x; acc.w += hi.y;
        }
        eb += 8;
    }
    for (int e = eb + grp; e < end; e += 2) {
        uint2 u = ((const uint2*)hsh)[(long)csr16[e] * 32 + q];
        float2 lo = __half22float2(*(__half2*)&u.x);
        float2 hi = __half22float2(*(__half2*)&u.y);
        acc.x += lo.x; acc.y += lo.y; acc.z += hi.x; acc.w += hi.y;
    }
    acc.x += __shfl_down(acc.x, 32);
    acc.y += __shfl_down(acc.y, 32);
    acc.z += __shfl_down(acc.z, 32);
    acc.w += __shfl_down(acc.w, 32);
    if (grp == 0) {
        float di = dinv[node];
        float4 b = ((const float4*)bias)[q];
        __half2 h01 = __floats2half2_rn(fmaxf(acc.x * di + b.x, 0.f), fmaxf(acc.y * di + b.y, 0.f));
        __half2 h23 = __floats2half2_rn(fmaxf(acc.z * di + b.z, 0.f), fmaxf(acc.w * di + b.w, 0.f));
        uint2 u = make_uint2(*(unsigned int*)&h01, *(unsigned int*)&h23);
        ((uint2*)outh)[(long)node * 32 + q] = u;
    }
}

// ---------------- folded layer 3 + pool + head ----------------

__global__ void w3l_kernel(const float* __restrict__ W3, const float* __restrict__ Wl,
                           const float* __restrict__ b3, float* __restrict__ W3l,
                           float* __restrict__ b3l) {
    __shared__ float Wls[HIDDEN * NCLS];
    int tid = threadIdx.x;
    for (int i = tid; i < HIDDEN * NCLS; i += 256) Wls[i] = Wl[i];
    __syncthreads();
    if (blockIdx.x < 10) {
        int o = blockIdx.x * 256 + tid;
        if (o < HIDDEN * NCLS) {
            int i = o / NCLS, j = o % NCLS;
            float acc = 0.f;
#pragma unroll 8
            for (int k = 0; k < HIDDEN; ++k) acc += W3[i * HIDDEN + k] * Wls[k * NCLS + j];
            W3l[o] = acc;
        }
    } else if (tid < NCLS) {
        float acc = 0.f;
#pragma unroll 8
        for (int k = 0; k < HIDDEN; ++k) acc += b3[k] * Wls[k * NCLS + tid];
        b3l[tid] = acc;
    }
}

// y32h[n,32] = (h2h @ W3l)*dinv, cols 19..31 zero; 12 nodes/block; h2 fp16 in
__global__ void gemm_y32h_kernel(const __half* __restrict__ h2h, const float* __restrict__ W3l,
                                 const float* __restrict__ dinv, __half* __restrict__ ys, int n) {
    __shared__ float hs[12][HIDDEN];
    __shared__ float Ws[HIDDEN][20];
    int tid = threadIdx.x;
    long base = (long)blockIdx.x * 12;
    for (int i = tid; i < HIDDEN * NCLS; i += 256) Ws[i / NCLS][i % NCLS] = W3l[i];
    for (int idx = tid; idx < 12 * 32; idx += 256) {
        int node = idx >> 5, q = idx & 31;
        long gn = base + node;
        uint2 u = (gn < n) ? ((const uint2*)h2h)[gn * 32 + q] : make_uint2(0u, 0u);
        float2 lo = __half22float2(*(__half2*)&u.x);
        float2 hi = __half22float2(*(__half2*)&u.y);
        hs[node][q * 4] = lo.x; hs[node][q * 4 + 1] = lo.y;
        hs[node][q * 4 + 2] = hi.x; hs[node][q * 4 + 3] = hi.y;
    }
    __syncthreads();
    if (tid < 12 * NCLS) {
        int node = tid / NCLS, j = tid % NCLS;
        long gn = base + node;
        if (gn < n) {
            float acc = 0.f;
#pragma unroll 8
            for (int k = 0; k < HIDDEN; ++k) acc += hs[node][k] * Ws[k][j];
            ys[gn * 32 + j] = __float2half(acc * dinv[gn]);
        }
    }
    for (int idx = tid; idx < 12 * 13; idx += 256) {
        int node = idx / 13, j = 19 + idx % 13;
        long gn = base + node;
        if (gn < n) ys[gn * 32 + j] = __half(0.f);
    }
}

__global__ void agg24h_pool_kernel(const __half* __restrict__ ys, const int2* __restrict__ begend,
                                   const unsigned short* __restrict__ csr16, const float* __restrict__ dinv,
                                   const int* __restrict__ batch, float* __restrict__ pool, int n) {
    int node = (int)(((long)blockIdx.x * blockDim.x + threadIdx.x) >> 6);
    int lane = threadIdx.x & 63;
    if (node >= n) return;
    int grp = lane >> 4, f = lane & 15;
    int2 be = begend[node];
    int beg = be.x, end = be.y;
    float2 acc = {0.f, 0.f};
    int eb = beg;
    for (; eb + 32 <= end; eb += 32) {
        int s[8]; unsigned int u[8];
#pragma unroll
        for (int j = 0; j < 8; ++j) s[j] = csr16[eb + grp + 4 * j];
#pragma unroll
        for (int j = 0; j < 8; ++j) u[j] = ((const unsigned int*)ys)[(long)s[j] * 16 + f];
#pragma unroll
        for (int j = 0; j < 8; ++j) {
            float2 v = __half22float2(*(__half2*)&u[j]);
            acc.x += v.x; acc.y += v.y;
        }
    }
    if (eb + 16 <= end) {
        int s[4]; unsigned int u[4];
#pragma unroll
        for (int j = 0; j < 4; ++j) s[j] = csr16[eb + grp + 4 * j];
#pragma unroll
        for (int j = 0; j < 4; ++j) u[j] = ((const unsigned int*)ys)[(long)s[j] * 16 + f];
#pragma unroll
        for (int j = 0; j < 4; ++j) {
            float2 v = __half22float2(*(__half2*)&u[j]);
            acc.x += v.x; acc.y += v.y;
        }
        eb += 16;
    }
    for (int e = eb + grp; e < end; e += 4) {
        unsigned int u = ((const unsigned int*)ys)[(long)csr16[e] * 16 + f];
        float2 v = __half22float2(*(__half2*)&u);
        acc.x += v.x; acc.y += v.y;
    }
    acc.x += __shfl_down(acc.x, 32);
    acc.y += __shfl_down(acc.y, 32);
    acc.x += __shfl_down(acc.x, 16);
    acc.y += __shfl_down(acc.y, 16);
    if (lane < 16) {
        int g = batch[node];
        float sc = dinv[node];
        int c0 = 2 * f;
        if (c0 < NCLS) atomicAdd(&pool[(long)g * 24 + c0], acc.x * sc);
        if (c0 + 1 < NCLS) atomicAdd(&pool[(long)g * 24 + c0 + 1], acc.y * sc);
    }
}

__global__ void final_kernel(const float* __restrict__ pool, const float* __restrict__ cnt,
                             const float* __restrict__ b3l, const float* __restrict__ bl,
                             float* __restrict__ out, int G) {
    int i = blockIdx.x * blockDim.x + threadIdx.x;
    if (i >= G * NCLS) return;
    int g = i / NCLS, j = i % NCLS;
    float c = cnt[g];
    out[i] = (c > 0.f) ? pool[(long)g * 24 + j] / c + b3l[j] + bl[j] : bl[j];
}

// ---------------- launch ----------------

static inline size_t align256(size_t x) { return (x + 255) & ~(size_t)255; }

extern "C" void kernel_launch(void* const* d_in, const int* in_sizes, int n_in,
                              void* d_out, int out_size, void* d_ws, size_t ws_size,
                              hipStream_t stream) {
    const float* x    = (const float*)d_in[0];
    const int*   ei   = (const int*)d_in[1];
    const int*   batch= (const int*)d_in[2];
    const float* W1   = (const float*)d_in[3];
    const float* b1   = (const float*)d_in[4];
    const float* W2   = (const float*)d_in[5];
    const float* b2   = (const float*)d_in[6];
    const float* W3   = (const float*)d_in[7];
    const float* b3   = (const float*)d_in[8];
    const float* Wl   = (const float*)d_in[9];
    const float* bl   = (const float*)d_in[10];
    float* out = (float*)d_out;

    const int N = in_sizes[0] / F_IN;
    const int E = in_sizes[1] / 2;
    const int G = out_size / NCLS;
    const int* src = ei;
    const int* dst = ei + E;
    const int nSB = (E + EPB - 1) / EPB;
    const int nBK = (N + RNODES - 1) / RNODES;
    // cap: edges land only in buckets covering nodes < N, i.e. ~N/512 used
    // buckets -> mean E*512/N per used bucket (sigma ~ sqrt(mean)); +1024 slack.
    int cap = (int)((long long)E * RNODES / N) + 1024;
    if (cap + RNODES > OUTL_CAP) cap = OUTL_CAP - RNODES;
    const int rst = cap + RNODES;                    // csr16 region stride/bucket

    // workspace carve-up
    char* p = (char*)d_ws;
    size_t off = 0;
    unsigned int*   bents  = (unsigned int*)(p + off);   off = align256(off + (size_t)NB * cap * 4);
    unsigned short* csr16  = (unsigned short*)(p + off); off = align256(off + (size_t)NB * rst * 2);
    int2*           begend = (int2*)(p + off);           off = align256(off + (size_t)N * 8);
    float*          dinv   = (float*)(p + off);          off = align256(off + (size_t)N * 4);
    float*          x16    = (float*)(p + off);          off = align256(off + (size_t)N * 16 * 4);
    float*          z16    = (float*)(p + off);          off = align256(off + (size_t)N * 16 * 4);
    __half*         h1h    = (__half*)(p + off);         off = align256(off + (size_t)N * HIDDEN * 2);
    __half*         hsh    = (__half*)(p + off);         off = align256(off + (size_t)N * HIDDEN * 2);
    __half*         h2h    = (__half*)(p + off);         off = align256(off + (size_t)N * HIDDEN * 2);
    __half*         y32h   = (__half*)(p + off);         off = align256(off + (size_t)N * 32 * 2);
    float*          W3l    = (float*)(p + off);          off = align256(off + (size_t)HIDDEN * NCLS * 4);
    float*          b3l    = (float*)(p + off);          off = align256(off + (size_t)NCLS * 4);
    float*          pool   = (float*)(p + off);
    float*          gcnt   = pool + (size_t)G * 24;
    int*            bcur   = (int*)(pool + (size_t)G * 25);  // adjacent: one memset covers all
    off = align256(off + (size_t)G * 25 * 4 + NB * 4);
    (void)ws_size; (void)n_in;

    // one memset zeroes pool, gcnt, and bcur
    hipMemsetAsync(pool, 0, (size_t)G * 25 * 4 + NB * 4, stream);

    // CSR build: scatter (capacity-padded append) -> build
    scatter_kernel<<<nSB, 256, 0, stream>>>(src, dst, bcur, bents, E, cap);
    build_kernel<<<nBK, 1024, 0, stream>>>(bents, bcur, x, batch, begend, csr16,
                                           dinv, gcnt, x16, N, cap, rst);
    w3l_kernel<<<11, 256, 0, stream>>>(W3, Wl, b3, W3l, b3l);

    const int aggBlocks = (N + 3) / 4;  // 4 waves/block, wave per node

    // layer 1: z16 = dinv * sum(x16) ; h1 = relu(z16@W1+b1) -> fp16
    agg16_kernel<<<aggBlocks, 256, 0, stream>>>(x16, begend, csr16, dinv, z16, N);
    gemm_in_kernel<<<(N + 7) / 8, 256, 0, stream>>>(z16, W1, b1, h1h, N);

    // layer 2: hsh = half((h1@W2)*dinv) row-major [MFMA] ; h2h = relu(dinv*sum + b2) fp16
    gemm_mfma_kernel<<<(N + 63) / 64, 256, 0, stream>>>(h1h, W2, dinv, hsh, N);
    agg128h_kernel<<<aggBlocks, 256, 0, stream>>>(hsh, begend, csr16, dinv, b2, h2h, N);

    // folded layer 3 + pool
    gemm_y32h_kernel<<<(N + 11) / 12, 256, 0, stream>>>(h2h, W3l, dinv, y32h, N);
    agg24h_pool_kernel<<<aggBlocks, 256, 0, stream>>>(y32h, begend, csr16, dinv, batch, pool, N);
    final_kernel<<<(G * NCLS + 255) / 256, 256, 0, stream>>>(pool, gcnt, b3l, bl, out, G);
}

// Round 12
// 247.177 us; speedup vs baseline: 1.3224x; 1.0214x over previous
//
#include <hip/hip_runtime.h>
#include <hip/hip_bf16.h>
#include <hip/hip_fp16.h>

// GCN2: 3x GCNConv(relu,relu,none) + global_mean_pool + linear head.
// R12 = R11 + layer-1 fusion: x16 stored fp16 (1.6MB table -> per-XCD
// L2-resident gathers), and gemm_in folded into agg16 (z broadcast via
// shuffles, W1 in LDS) -> one kernel, no z16 round-trip.

#define HIDDEN 128
#define F_IN 11
#define NCLS 19
#define NBITS 9
#define NB 128
#define RNODES 512
#define EPB 8192
#define OUTL_CAP 10240

typedef _Float16 half8 __attribute__((ext_vector_type(8)));
typedef float floatx4 __attribute__((ext_vector_type(4)));

// ---------------- bucketed CSR build (2 kernels) ----------------

__global__ void scatter_kernel(const int* __restrict__ src, const int* __restrict__ dst,
                               int* __restrict__ bcur, unsigned int* __restrict__ bents,
                               int E, int cap) {
    __shared__ int hist[NB];
    __shared__ int binoff[NB];
    __shared__ int runrel[NB];
    __shared__ unsigned int ebuf[EPB];
    __shared__ unsigned short binOf[EPB];
    __shared__ int cw[2];
    int tid = threadIdx.x, lane = tid & 63, w = tid >> 6;
    int base = blockIdx.x * EPB;
    int cnt = min(EPB, E - base);
    for (int i = tid; i < NB; i += 256) hist[i] = 0;
    __syncthreads();
    unsigned int pk[32];
    int rk[32];
#pragma unroll
    for (int j = 0; j < 32; ++j) {
        int idx = tid + 256 * j;
        if (idx < cnt) {
            int e = base + idx;
            int s = src[e], d = dst[e];
            pk[j] = (unsigned int)s | ((unsigned int)d << 16);
            int bin = d >> NBITS;
            int r = atomicAdd(&hist[bin], 1);
            rk[j] = r | (bin << 16);
        } else rk[j] = -1;
    }
    __syncthreads();
    int v = 0, xv = 0;
    if (tid < NB) {
        v = hist[tid]; xv = v;
#pragma unroll
        for (int d = 1; d < 64; d <<= 1) {
            int t = __shfl_up(xv, d, 64);
            if (lane >= d) xv += t;
        }
        if (lane == 63) cw[w] = xv;
    }
    __syncthreads();
    if (tid < NB) {
        binoff[tid] = xv - v + ((w == 1) ? cw[0] : 0);
        runrel[tid] = v ? atomicAdd(&bcur[tid], v) : 0;
    }
    __syncthreads();
#pragma unroll
    for (int j = 0; j < 32; ++j) {
        if (rk[j] >= 0) {
            int bin = rk[j] >> 16, r = rk[j] & 0xFFFF;
            int pos = binoff[bin] + r;
            ebuf[pos] = pk[j];
            binOf[pos] = (unsigned short)bin;
        }
    }
    __syncthreads();
    for (int i = tid; i < cnt; i += 256) {
        int bin = binOf[i];
        int rel = runrel[bin] + (i - binoff[bin]);
        if (rel < cap)                          // hard guard: never cross regions
            bents[bin * cap + rel] = ebuf[i];
    }
}

// per bucket: counts -> scan -> LDS scatter (self + srcs) -> dense writes.
__global__ void build_kernel(const unsigned int* __restrict__ bents, const int* __restrict__ bcur,
                             const float* __restrict__ x, const int* __restrict__ batch,
                             int2* __restrict__ begend, unsigned short* __restrict__ csr16,
                             float* __restrict__ dinv, float* __restrict__ gcnt,
                             __half* __restrict__ x16h, int n, int cap, int rst) {
    __shared__ int counts[RNODES];
    __shared__ int lcur[RNODES];
    __shared__ unsigned short outl[OUTL_CAP];
    __shared__ int wsums[8];
    int tid = threadIdx.x;          // 1024
    int lane = tid & 63, w = tid >> 6;
    int b = blockIdx.x;
    int base = b << NBITS;
    int nn = min(RNODES, n - base);
    int ebase = b * cap;
    int ecnt = min(bcur[b], cap);   // hard guard
    int st = b * rst;
    for (int i = tid; i < RNODES; i += 1024) counts[i] = 0;
    __syncthreads();
    for (int e = tid; e < ecnt; e += 1024)
        atomicAdd(&counts[(bents[ebase + e] >> 16) - base], 1);
    __syncthreads();
    int v = 0, xv = 0;
    if (tid < RNODES) {
        v = (tid < nn) ? counts[tid] + 1 : 0;
        xv = v;
#pragma unroll
        for (int d = 1; d < 64; d <<= 1) {
            int t = __shfl_up(xv, d, 64);
            if (lane >= d) xv += t;
        }
        if (lane == 63) wsums[w] = xv;
    }
    __syncthreads();
    if (tid < 64) {
        int s = (lane < 8) ? wsums[lane] : 0;
#pragma unroll
        for (int d = 1; d < 8; d <<= 1) {
            int t = __shfl_up(s, d, 64);
            if (lane >= d) s += t;
        }
        if (lane < 8) wsums[lane] = s;
    }
    __syncthreads();
    if (tid < nn) {
        int excl = xv - v + ((w > 0) ? wsums[w - 1] : 0);
        lcur[tid] = excl + 1;
        outl[excl] = (unsigned short)(base + tid);        // self-loop slot 0
        begend[base + tid] = make_int2(st + excl, st + excl + v);
        atomicAdd(&gcnt[batch[base + tid]], 1.0f);
    }
    __syncthreads();
    for (int e = tid; e < ecnt; e += 1024) {
        unsigned int pk = bents[ebase + e];
        int i = (int)(pk >> 16) - base;
        int r = atomicAdd(&lcur[i], 1);
        outl[r] = (unsigned short)(pk & 0xFFFFu);
    }
    __syncthreads();
    int total = ecnt + nn;
    for (int i = tid; i < total; i += 1024)
        csr16[st + i] = outl[i];
    for (int idx = tid; idx < nn * 16; idx += 1024) {
        int i = idx >> 4, j = idx & 15;
        float di = 1.0f / sqrtf((float)(counts[i] + 1));
        if (j == 0) dinv[base + i] = di;
        float xv2 = (j < F_IN) ? x[(long)(base + i) * F_IN + j] * di : 0.f;
        x16h[(long)(base + i) * 16 + j] = __float2half(xv2);
    }
}

// ---------------- layer 1 fused: agg(x16h) + GEMM W1 + relu -> h1 fp16 ----------------
// wave per node: gather 16-wide (4 grp x 16 lanes), shuffle-reduce to z[0..15],
// then all 64 lanes compute 2 output cols each via z-broadcast shuffles.

__global__ void agg16_gemm_kernel(const __half* __restrict__ x16h, const int2* __restrict__ begend,
                                  const unsigned short* __restrict__ csr16,
                                  const float* __restrict__ dinv, const float* __restrict__ W1,
                                  const float* __restrict__ b1, __half* __restrict__ h1h, int n) {
    __shared__ float2 W1s[F_IN][64];
    __shared__ float2 bs[64];
    int tid = threadIdx.x;
    for (int i = tid; i < F_IN * 64; i += 256) {
        int k = i >> 6, j = i & 63;
        W1s[k][j] = make_float2(W1[k * HIDDEN + 2 * j], W1[k * HIDDEN + 2 * j + 1]);
    }
    if (tid < 64) bs[tid] = make_float2(b1[2 * tid], b1[2 * tid + 1]);
    __syncthreads();
    int node = (int)(((long)blockIdx.x * blockDim.x + threadIdx.x) >> 6);
    int lane = threadIdx.x & 63;
    if (node >= n) return;
    int grp = lane >> 4, f = lane & 15;
    int2 be = begend[node];
    int beg = be.x, end = be.y;
    float acc = 0.f;
    int eb = beg;
    for (; eb + 16 <= end; eb += 16) {
        int s[4]; __half v[4];
#pragma unroll
        for (int j = 0; j < 4; ++j) s[j] = csr16[eb + grp + 4 * j];
#pragma unroll
        for (int j = 0; j < 4; ++j) v[j] = x16h[(long)s[j] * 16 + f];
#pragma unroll
        for (int j = 0; j < 4; ++j) acc += __half2float(v[j]);
    }
    if (eb + 8 <= end) {
        int s0 = csr16[eb + grp], s1 = csr16[eb + grp + 4];
        acc += __half2float(x16h[(long)s0 * 16 + f]) + __half2float(x16h[(long)s1 * 16 + f]);
        eb += 8;
    }
    for (int e = eb + grp; e < end; e += 4)
        acc += __half2float(x16h[(long)csr16[e] * 16 + f]);
    acc += __shfl_down(acc, 32);
    acc += __shfl_down(acc, 16);
    float z = acc * dinv[node];          // valid in lanes 0..15
    // GEMM: lane computes cols 2*lane, 2*lane+1
    float2 o = bs[lane];
#pragma unroll
    for (int k = 0; k < F_IN; ++k) {
        float zk = __shfl(z, k);
        float2 w = W1s[k][lane];
        o.x += zk * w.x;
        o.y += zk * w.y;
    }
    __half2 h = __floats2half2_rn(fmaxf(o.x, 0.f), fmaxf(o.y, 0.f));
    ((__half2*)h1h)[(long)node * 64 + lane] = h;
}

// ---------------- layer-2 GEMM: MFMA f16, ROW-major fp16 output ----------------

__global__ __launch_bounds__(256) void gemm_mfma_kernel(
        const __half* __restrict__ h1h, const float* __restrict__ W2,
        const float* __restrict__ dinv, __half* __restrict__ hsh, int n) {
    __shared__ _Float16 W2T[128 * 136];    // [n][k], stride 136
    __shared__ _Float16 outs[64 * 136];    // [node][feat], stride 136
    int tid = threadIdx.x;
    for (int i = tid; i < 128 * 128; i += 256) {
        int k = i >> 7, nn = i & 127;
        W2T[nn * 136 + k] = (_Float16)W2[i];
    }
    int base = blockIdx.x * 64;
    int lane = tid & 63, wid = tid >> 6;
    int l15 = lane & 15, quad = lane >> 4;
    int arow = base + wid * 16 + l15;
    if (arow >= n) arow = n - 1;           // clamp: safe reads, invalid rows unwritten
    const _Float16* Aptr = (const _Float16*)h1h + (size_t)arow * 128;
    floatx4 acc[8];
#pragma unroll
    for (int t = 0; t < 8; ++t) acc[t] = (floatx4){0.f, 0.f, 0.f, 0.f};
    __syncthreads();
#pragma unroll
    for (int c = 0; c < 4; ++c) {
        half8 a = *(const half8*)(Aptr + c * 32 + quad * 8);
#pragma unroll
        for (int t = 0; t < 8; ++t) {
            half8 b = *(const half8*)(&W2T[(t * 16 + l15) * 136 + c * 32 + quad * 8]);
            acc[t] = __builtin_amdgcn_mfma_f32_16x16x32_f16(a, b, acc[t], 0, 0, 0);
        }
    }
    float dv[4];
#pragma unroll
    for (int r = 0; r < 4; ++r) {
        int nd = base + wid * 16 + quad * 4 + r;
        dv[r] = dinv[(nd < n) ? nd : 0];
    }
#pragma unroll
    for (int t = 0; t < 8; ++t)
#pragma unroll
        for (int r = 0; r < 4; ++r)
            outs[(wid * 16 + quad * 4 + r) * 136 + t * 16 + l15] = (_Float16)(acc[t][r] * dv[r]);
    __syncthreads();
    for (int i = tid; i < 64 * 16; i += 256) {
        int ln = i >> 4, qq = i & 15;
        long nd = base + ln;
        if (nd < n) {
            uint4 u = *(uint4*)&outs[ln * 136 + qq * 8];
            ((uint4*)hsh)[nd * 16 + qq] = u;
        }
    }
}

// ---------------- 128-wide agg (layer 2): half in, half out ----------------

__global__ void agg128h_kernel(const __half* __restrict__ hsh, const int2* __restrict__ begend,
                               const unsigned short* __restrict__ csr16, const float* __restrict__ dinv,
                               const float* __restrict__ bias, __half* __restrict__ outh, int n) {
    int node = (int)(((long)blockIdx.x * blockDim.x + threadIdx.x) >> 6);
    int lane = threadIdx.x & 63;
    if (node >= n) return;
    int grp = lane >> 5, q = lane & 31;
    int2 be = begend[node];
    int beg = be.x, end = be.y;
    float4 acc = make_float4(0.f, 0.f, 0.f, 0.f);
    int eb = beg;
    for (; eb + 16 <= end; eb += 16) {
        int s[8]; uint2 u[8];
#pragma unroll
        for (int j = 0; j < 8; ++j) s[j] = csr16[eb + grp + 2 * j];
#pragma unroll
        for (int j = 0; j < 8; ++j) u[j] = ((const uint2*)hsh)[(long)s[j] * 32 + q];
#pragma unroll
        for (int j = 0; j < 8; ++j) {
            float2 lo = __half22float2(*(__half2*)&u[j].x);
            float2 hi = __half22float2(*(__half2*)&u[j].y);
            acc.x += lo.x; acc.y += lo.y; acc.z += hi.x; acc.w += hi.y;
        }
    }
    if (eb + 8 <= end) {
        int s[4]; uint2 u[4];
#pragma unroll
        for (int j = 0; j < 4; ++j) s[j] = csr16[eb + grp + 2 * j];
#pragma unroll
        for (int j = 0; j < 4; ++j) u[j] = ((const uint2*)hsh)[(long)s[j] * 32 + q];
#pragma unroll
        for (int j = 0; j < 4; ++j) {
            float2 lo = __half22float2(*(__half2*)&u[j].x);
            float2 hi = __half22float2(*(__half2*)&u[j].y);
            acc.x += lo.x; acc.y += lo.y; acc.z += hi.x; acc.w += hi.y;
        }
        eb += 8;
    }
    for (int e = eb + grp; e < end; e += 2) {
        uint2 u = ((const uint2*)hsh)[(long)csr16[e] * 32 + q];
        float2 lo = __half22float2(*(__half2*)&u.x);
        float2 hi = __half22float2(*(__half2*)&u.y);
        acc.x += lo.x; acc.y += lo.y; acc.z += hi.x; acc.w += hi.y;
    }
    acc.x += __shfl_down(acc.x, 32);
    acc.y += __shfl_down(acc.y, 32);
    acc.z += __shfl_down(acc.z, 32);
    acc.w += __shfl_down(acc.w, 32);
    if (grp == 0) {
        float di = dinv[node];
        float4 b = ((const float4*)bias)[q];
        __half2 h01 = __floats2half2_rn(fmaxf(acc.x * di + b.x, 0.f), fmaxf(acc.y * di + b.y, 0.f));
        __half2 h23 = __floats2half2_rn(fmaxf(acc.z * di + b.z, 0.f), fmaxf(acc.w * di + b.w, 0.f));
        uint2 u = make_uint2(*(unsigned int*)&h01, *(unsigned int*)&h23);
        ((uint2*)outh)[(long)node * 32 + q] = u;
    }
}

// ---------------- folded layer 3 + pool + head ----------------

__global__ void w3l_kernel(const float* __restrict__ W3, const float* __restrict__ Wl,
                           const float* __restrict__ b3, float* __restrict__ W3l,
                           float* __restrict__ b3l) {
    __shared__ float Wls[HIDDEN * NCLS];
    int tid = threadIdx.x;
    for (int i = tid; i < HIDDEN * NCLS; i += 256) Wls[i] = Wl[i];
    __syncthreads();
    if (blockIdx.x < 10) {
        int o = blockIdx.x * 256 + tid;
        if (o < HIDDEN * NCLS) {
            int i = o / NCLS, j = o % NCLS;
            float acc = 0.f;
#pragma unroll 8
            for (int k = 0; k < HIDDEN; ++k) acc += W3[i * HIDDEN + k] * Wls[k * NCLS + j];
            W3l[o] = acc;
        }
    } else if (tid < NCLS) {
        float acc = 0.f;
#pragma unroll 8
        for (int k = 0; k < HIDDEN; ++k) acc += b3[k] * Wls[k * NCLS + tid];
        b3l[tid] = acc;
    }
}

// y32h[n,32] = (h2h @ W3l)*dinv, cols 19..31 zero; 12 nodes/block; h2 fp16 in
__global__ void gemm_y32h_kernel(const __half* __restrict__ h2h, const float* __restrict__ W3l,
                                 const float* __restrict__ dinv, __half* __restrict__ ys, int n) {
    __shared__ float hs[12][HIDDEN];
    __shared__ float Ws[HIDDEN][20];
    int tid = threadIdx.x;
    long base = (long)blockIdx.x * 12;
    for (int i = tid; i < HIDDEN * NCLS; i += 256) Ws[i / NCLS][i % NCLS] = W3l[i];
    for (int idx = tid; idx < 12 * 32; idx += 256) {
        int node = idx >> 5, q = idx & 31;
        long gn = base + node;
        uint2 u = (gn < n) ? ((const uint2*)h2h)[gn * 32 + q] : make_uint2(0u, 0u);
        float2 lo = __half22float2(*(__half2*)&u.x);
        float2 hi = __half22float2(*(__half2*)&u.y);
        hs[node][q * 4] = lo.x; hs[node][q * 4 + 1] = lo.y;
        hs[node][q * 4 + 2] = hi.x; hs[node][q * 4 + 3] = hi.y;
    }
    __syncthreads();
    if (tid < 12 * NCLS) {
        int node = tid / NCLS, j = tid % NCLS;
        long gn = base + node;
        if (gn < n) {
            float acc = 0.f;
#pragma unroll 8
            for (int k = 0; k < HIDDEN; ++k) acc += hs[node][k] * Ws[k][j];
            ys[gn * 32 + j] = __float2half(acc * dinv[gn]);
        }
    }
    for (int idx = tid; idx < 12 * 13; idx += 256) {
        int node = idx / 13, j = 19 + idx % 13;
        long gn = base + node;
        if (gn < n) ys[gn * 32 + j] = __half(0.f);
    }
}

__global__ void agg24h_pool_kernel(const __half* __restrict__ ys, const int2* __restrict__ begend,
                                   const unsigned short* __restrict__ csr16, const float* __restrict__ dinv,
                                   const int* __restrict__ batch, float* __restrict__ pool, int n) {
    int node = (int)(((long)blockIdx.x * blockDim.x + threadIdx.x) >> 6);
    int lane = threadIdx.x & 63;
    if (node >= n) return;
    int grp = lane >> 4, f = lane & 15;
    int2 be = begend[node];
    int beg = be.x, end = be.y;
    float2 acc = {0.f, 0.f};
    int eb = beg;
    for (; eb + 32 <= end; eb += 32) {
        int s[8]; unsigned int u[8];
#pragma unroll
        for (int j = 0; j < 8; ++j) s[j] = csr16[eb + grp + 4 * j];
#pragma unroll
        for (int j = 0; j < 8; ++j) u[j] = ((const unsigned int*)ys)[(long)s[j] * 16 + f];
#pragma unroll
        for (int j = 0; j < 8; ++j) {
            float2 v = __half22float2(*(__half2*)&u[j]);
            acc.x += v.x; acc.y += v.y;
        }
    }
    if (eb + 16 <= end) {
        int s[4]; unsigned int u[4];
#pragma unroll
        for (int j = 0; j < 4; ++j) s[j] = csr16[eb + grp + 4 * j];
#pragma unroll
        for (int j = 0; j < 4; ++j) u[j] = ((const unsigned int*)ys)[(long)s[j] * 16 + f];
#pragma unroll
        for (int j = 0; j < 4; ++j) {
            float2 v = __half22float2(*(__half2*)&u[j]);
            acc.x += v.x; acc.y += v.y;
        }
        eb += 16;
    }
    for (int e = eb + grp; e < end; e += 4) {
        unsigned int u = ((const unsigned int*)ys)[(long)csr16[e] * 16 + f];
        float2 v = __half22float2(*(__half2*)&u);
        acc.x += v.x; acc.y += v.y;
    }
    acc.x += __shfl_down(acc.x, 32);
    acc.y += __shfl_down(acc.y, 32);
    acc.x += __shfl_down(acc.x, 16);
    acc.y += __shfl_down(acc.y, 16);
    if (lane < 16) {
        int g = batch[node];
        float sc = dinv[node];
        int c0 = 2 * f;
        if (c0 < NCLS) atomicAdd(&pool[(long)g * 24 + c0], acc.x * sc);
        if (c0 + 1 < NCLS) atomicAdd(&pool[(long)g * 24 + c0 + 1], acc.y * sc);
    }
}

__global__ void final_kernel(const float* __restrict__ pool, const float* __restrict__ cnt,
                             const float* __restrict__ b3l, const float* __restrict__ bl,
                             float* __restrict__ out, int G) {
    int i = blockIdx.x * blockDim.x + threadIdx.x;
    if (i >= G * NCLS) return;
    int g = i / NCLS, j = i % NCLS;
    float c = cnt[g];
    out[i] = (c > 0.f) ? pool[(long)g * 24 + j] / c + b3l[j] + bl[j] : bl[j];
}

// ---------------- launch ----------------

static inline size_t align256(size_t x) { return (x + 255) & ~(size_t)255; }

extern "C" void kernel_launch(void* const* d_in, const int* in_sizes, int n_in,
                              void* d_out, int out_size, void* d_ws, size_t ws_size,
                              hipStream_t stream) {
    const float* x    = (const float*)d_in[0];
    const int*   ei   = (const int*)d_in[1];
    const int*   batch= (const int*)d_in[2];
    const float* W1   = (const float*)d_in[3];
    const float* b1   = (const float*)d_in[4];
    const float* W2   = (const float*)d_in[5];
    const float* b2   = (const float*)d_in[6];
    const float* W3   = (const float*)d_in[7];
    const float* b3   = (const float*)d_in[8];
    const float* Wl   = (const float*)d_in[9];
    const float* bl   = (const float*)d_in[10];
    float* out = (float*)d_out;

    const int N = in_sizes[0] / F_IN;
    const int E = in_sizes[1] / 2;
    const int G = out_size / NCLS;
    const int* src = ei;
    const int* dst = ei + E;
    const int nSB = (E + EPB - 1) / EPB;
    const int nBK = (N + RNODES - 1) / RNODES;
    // cap: mean edges per USED bucket is E*512/N (only ~N/512 buckets populated)
    int cap = (int)((long long)E * RNODES / N) + 1024;
    if (cap + RNODES > OUTL_CAP) cap = OUTL_CAP - RNODES;
    const int rst = cap + RNODES;

    // workspace carve-up
    char* p = (char*)d_ws;
    size_t off = 0;
    unsigned int*   bents  = (unsigned int*)(p + off);   off = align256(off + (size_t)NB * cap * 4);
    unsigned short* csr16  = (unsigned short*)(p + off); off = align256(off + (size_t)NB * rst * 2);
    int2*           begend = (int2*)(p + off);           off = align256(off + (size_t)N * 8);
    float*          dinv   = (float*)(p + off);          off = align256(off + (size_t)N * 4);
    __half*         x16h   = (__half*)(p + off);         off = align256(off + (size_t)N * 16 * 2);
    __half*         h1h    = (__half*)(p + off);         off = align256(off + (size_t)N * HIDDEN * 2);
    __half*         hsh    = (__half*)(p + off);         off = align256(off + (size_t)N * HIDDEN * 2);
    __half*         h2h    = (__half*)(p + off);         off = align256(off + (size_t)N * HIDDEN * 2);
    __half*         y32h   = (__half*)(p + off);         off = align256(off + (size_t)N * 32 * 2);
    float*          W3l    = (float*)(p + off);          off = align256(off + (size_t)HIDDEN * NCLS * 4);
    float*          b3l    = (float*)(p + off);          off = align256(off + (size_t)NCLS * 4);
    float*          pool   = (float*)(p + off);
    float*          gcnt   = pool + (size_t)G * 24;
    int*            bcur   = (int*)(pool + (size_t)G * 25);  // adjacent: one memset covers all
    off = align256(off + (size_t)G * 25 * 4 + NB * 4);
    (void)ws_size; (void)n_in;

    // one memset zeroes pool, gcnt, and bcur
    hipMemsetAsync(pool, 0, (size_t)G * 25 * 4 + NB * 4, stream);

    // CSR build: scatter (capacity-padded append) -> build
    scatter_kernel<<<nSB, 256, 0, stream>>>(src, dst, bcur, bents, E, cap);
    build_kernel<<<nBK, 1024, 0, stream>>>(bents, bcur, x, batch, begend, csr16,
                                           dinv, gcnt, x16h, N, cap, rst);
    w3l_kernel<<<11, 256, 0, stream>>>(W3, Wl, b3, W3l, b3l);

    const int aggBlocks = (N + 3) / 4;  // 4 waves/block, wave per node

    // layer 1 fused: h1 = relu((dinv*sum x16h)@W1 + b1) -> fp16
    agg16_gemm_kernel<<<aggBlocks, 256, 0, stream>>>(x16h, begend, csr16, dinv, W1, b1, h1h, N);

    // layer 2: hsh = half((h1@W2)*dinv) row-major [MFMA] ; h2h = relu(dinv*sum + b2) fp16
    gemm_mfma_kernel<<<(N + 63) / 64, 256, 0, stream>>>(h1h, W2, dinv, hsh, N);
    agg128h_kernel<<<aggBlocks, 256, 0, stream>>>(hsh, begend, csr16, dinv, b2, h2h, N);

    // folded layer 3 + pool
    gemm_y32h_kernel<<<(N + 11) / 12, 256, 0, stream>>>(h2h, W3l, dinv, y32h, N);
    agg24h_pool_kernel<<<aggBlocks, 256, 0, stream>>>(y32h, begend, csr16, dinv, batch, pool, N);
    final_kernel<<<(G * NCLS + 255) / 256, 256, 0, stream>>>(pool, gcnt, b3l, bl, out, G);
}

// Round 13
// 231.615 us; speedup vs baseline: 1.4113x; 1.0672x over previous
//
#include <hip/hip_runtime.h>
#include <hip/hip_bf16.h>
#include <hip/hip_fp16.h>

// GCN2: 3x GCNConv(relu,relu,none) + global_mean_pool + linear head.
// R13 = R12 + CSR-chain parallelism: 256 buckets of 256 nodes (NBITS=8),
// EPB=4096 -> scatter/build both ~196 blocks (was 98, 38% occupancy).
// w3l folded into scatter's grid (+15 blocks), which also pre-converts
// W2 -> fp16 transposed so gemm_mfma stages via uint4 copies.

#define HIDDEN 128
#define F_IN 11
#define NCLS 19
#define NBITS 8
#define NB 256
#define RNODES 256
#define EPB 4096
#define OUTL_CAP 5376

typedef _Float16 half8 __attribute__((ext_vector_type(8)));
typedef float floatx4 __attribute__((ext_vector_type(4)));

// ---------------- scatter (+ folded w3l / W2 conversion blocks) ----------------

__global__ void scatter_kernel(const int* __restrict__ src, const int* __restrict__ dst,
                               int* __restrict__ bcur, unsigned int* __restrict__ bents,
                               int E, int cap, int nSB,
                               const float* __restrict__ W3, const float* __restrict__ Wl,
                               const float* __restrict__ b3, float* __restrict__ W3l,
                               float* __restrict__ b3l, const float* __restrict__ W2,
                               __half* __restrict__ W2Th) {
    __shared__ int hist[NB];
    __shared__ int binoff[NB];
    __shared__ int runrel[NB];
    __shared__ unsigned int ebuf[EPB];
    __shared__ unsigned short binOf[EPB];
    __shared__ int cw[4];
    int tid = threadIdx.x, lane = tid & 63, w = tid >> 6;

    if (blockIdx.x >= nSB) {                 // ---- folded precompute blocks ----
        int xb = blockIdx.x - nSB;
        if (xb < 11) {
            float* Wls = (float*)ebuf;       // alias: 128*19 floats = 9.7KB
            for (int i = tid; i < HIDDEN * NCLS; i += 256) Wls[i] = Wl[i];
            __syncthreads();
            if (xb < 10) {
                int o = xb * 256 + tid;
                if (o < HIDDEN * NCLS) {
                    int i = o / NCLS, j = o % NCLS;
                    float acc = 0.f;
#pragma unroll 8
                    for (int k = 0; k < HIDDEN; ++k) acc += W3[i * HIDDEN + k] * Wls[k * NCLS + j];
                    W3l[o] = acc;
                }
            } else if (tid < NCLS) {
                float acc = 0.f;
#pragma unroll 8
                for (int k = 0; k < HIDDEN; ++k) acc += b3[k] * Wls[k * NCLS + tid];
                b3l[tid] = acc;
            }
        } else {                              // xb 11..14: W2Th[n][k] = fp16(W2[k][n])
            int base = (xb - 11) * 4096;
#pragma unroll
            for (int r = 0; r < 16; ++r) {
                int idx = base + tid + 256 * r;
                int k = idx >> 7, nn2 = idx & 127;
                W2Th[nn2 * HIDDEN + k] = __float2half(W2[idx]);
            }
        }
        return;
    }

    // ---- scatter proper ----
    int base = blockIdx.x * EPB;
    int cnt = min(EPB, E - base);
    for (int i = tid; i < NB; i += 256) hist[i] = 0;
    __syncthreads();
    unsigned int pk[16];
    int rk[16];
#pragma unroll
    for (int j = 0; j < 16; ++j) {
        int idx = tid + 256 * j;
        if (idx < cnt) {
            int e = base + idx;
            int s = src[e], d = dst[e];
            pk[j] = (unsigned int)s | ((unsigned int)d << 16);
            int bin = d >> NBITS;
            int r = atomicAdd(&hist[bin], 1);
            rk[j] = r | (bin << 16);
        } else rk[j] = -1;
    }
    __syncthreads();
    int v = hist[tid], xv = v;                 // 256 threads scan 256 bins
#pragma unroll
    for (int d = 1; d < 64; d <<= 1) {
        int t = __shfl_up(xv, d, 64);
        if (lane >= d) xv += t;
    }
    if (lane == 63) cw[w] = xv;
    __syncthreads();
    int waveoff = 0;
    for (int wi = 0; wi < w; ++wi) waveoff += cw[wi];
    binoff[tid] = waveoff + xv - v;
    runrel[tid] = v ? atomicAdd(&bcur[tid], v) : 0;
    __syncthreads();
#pragma unroll
    for (int j = 0; j < 16; ++j) {
        if (rk[j] >= 0) {
            int bin = rk[j] >> 16, r = rk[j] & 0xFFFF;
            int pos = binoff[bin] + r;
            ebuf[pos] = pk[j];
            binOf[pos] = (unsigned short)bin;
        }
    }
    __syncthreads();
    for (int i = tid; i < cnt; i += 256) {
        int bin = binOf[i];
        int rel = runrel[bin] + (i - binoff[bin]);
        if (rel < cap)                          // hard guard: never cross regions
            bents[bin * cap + rel] = ebuf[i];
    }
}

// per bucket (256 nodes): counts -> scan -> LDS scatter -> dense writes. 512 threads.
__global__ void build_kernel(const unsigned int* __restrict__ bents, const int* __restrict__ bcur,
                             const float* __restrict__ x, const int* __restrict__ batch,
                             int2* __restrict__ begend, unsigned short* __restrict__ csr16,
                             float* __restrict__ dinv, float* __restrict__ gcnt,
                             __half* __restrict__ x16h, int n, int cap, int rst) {
    __shared__ int counts[RNODES];
    __shared__ int lcur[RNODES];
    __shared__ unsigned short outl[OUTL_CAP];
    __shared__ int wsums[4];
    int tid = threadIdx.x;          // 512
    int lane = tid & 63, w = tid >> 6;
    int b = blockIdx.x;
    int base = b << NBITS;
    int nn = min(RNODES, n - base);
    int ebase = b * cap;
    int ecnt = min(bcur[b], cap);   // hard guard
    int st = b * rst;
    for (int i = tid; i < RNODES; i += 512) counts[i] = 0;
    __syncthreads();
    for (int e = tid; e < ecnt; e += 512)
        atomicAdd(&counts[(bents[ebase + e] >> 16) - base], 1);
    __syncthreads();
    int v = 0, xv = 0;
    if (tid < RNODES) {             // 4 waves scan 256 entries
        v = (tid < nn) ? counts[tid] + 1 : 0;
        xv = v;
#pragma unroll
        for (int d = 1; d < 64; d <<= 1) {
            int t = __shfl_up(xv, d, 64);
            if (lane >= d) xv += t;
        }
        if (lane == 63) wsums[w] = xv;
    }
    __syncthreads();
    if (tid < nn) {
        int waveoff = 0;
        for (int wi = 0; wi < w; ++wi) waveoff += wsums[wi];
        int excl = waveoff + xv - v;
        lcur[tid] = excl + 1;
        outl[excl] = (unsigned short)(base + tid);        // self-loop slot 0
        begend[base + tid] = make_int2(st + excl, st + excl + v);
        atomicAdd(&gcnt[batch[base + tid]], 1.0f);
    }
    __syncthreads();
    for (int e = tid; e < ecnt; e += 512) {
        unsigned int pk = bents[ebase + e];
        int i = (int)(pk >> 16) - base;
        int r = atomicAdd(&lcur[i], 1);
        outl[r] = (unsigned short)(pk & 0xFFFFu);
    }
    __syncthreads();
    int total = ecnt + nn;
    for (int i = tid; i < total; i += 512)
        csr16[st + i] = outl[i];
    for (int idx = tid; idx < nn * 16; idx += 512) {
        int i = idx >> 4, j = idx & 15;
        float di = 1.0f / sqrtf((float)(counts[i] + 1));
        if (j == 0) dinv[base + i] = di;
        float xv2 = (j < F_IN) ? x[(long)(base + i) * F_IN + j] * di : 0.f;
        x16h[(long)(base + i) * 16 + j] = __float2half(xv2);
    }
}

// ---------------- layer 1 fused: agg(x16h) + GEMM W1 + relu -> h1 fp16 ----------------

__global__ void agg16_gemm_kernel(const __half* __restrict__ x16h, const int2* __restrict__ begend,
                                  const unsigned short* __restrict__ csr16,
                                  const float* __restrict__ dinv, const float* __restrict__ W1,
                                  const float* __restrict__ b1, __half* __restrict__ h1h, int n) {
    __shared__ float2 W1s[F_IN][64];
    __shared__ float2 bs[64];
    int tid = threadIdx.x;
    for (int i = tid; i < F_IN * 64; i += 256) {
        int k = i >> 6, j = i & 63;
        W1s[k][j] = make_float2(W1[k * HIDDEN + 2 * j], W1[k * HIDDEN + 2 * j + 1]);
    }
    if (tid < 64) bs[tid] = make_float2(b1[2 * tid], b1[2 * tid + 1]);
    __syncthreads();
    int node = (int)(((long)blockIdx.x * blockDim.x + threadIdx.x) >> 6);
    int lane = threadIdx.x & 63;
    if (node >= n) return;
    int grp = lane >> 4, f = lane & 15;
    int2 be = begend[node];
    int beg = be.x, end = be.y;
    float acc = 0.f;
    int eb = beg;
    for (; eb + 16 <= end; eb += 16) {
        int s[4]; __half v[4];
#pragma unroll
        for (int j = 0; j < 4; ++j) s[j] = csr16[eb + grp + 4 * j];
#pragma unroll
        for (int j = 0; j < 4; ++j) v[j] = x16h[(long)s[j] * 16 + f];
#pragma unroll
        for (int j = 0; j < 4; ++j) acc += __half2float(v[j]);
    }
    if (eb + 8 <= end) {
        int s0 = csr16[eb + grp], s1 = csr16[eb + grp + 4];
        acc += __half2float(x16h[(long)s0 * 16 + f]) + __half2float(x16h[(long)s1 * 16 + f]);
        eb += 8;
    }
    for (int e = eb + grp; e < end; e += 4)
        acc += __half2float(x16h[(long)csr16[e] * 16 + f]);
    acc += __shfl_down(acc, 32);
    acc += __shfl_down(acc, 16);
    float z = acc * dinv[node];          // valid in lanes 0..15
    float2 o = bs[lane];
#pragma unroll
    for (int k = 0; k < F_IN; ++k) {
        float zk = __shfl(z, k);
        float2 w = W1s[k][lane];
        o.x += zk * w.x;
        o.y += zk * w.y;
    }
    __half2 h = __floats2half2_rn(fmaxf(o.x, 0.f), fmaxf(o.y, 0.f));
    ((__half2*)h1h)[(long)node * 64 + lane] = h;
}

// ---------------- layer-2 GEMM: MFMA f16, W2Th pre-converted ----------------

__global__ __launch_bounds__(256) void gemm_mfma_kernel(
        const __half* __restrict__ h1h, const __half* __restrict__ W2Th,
        const float* __restrict__ dinv, __half* __restrict__ hsh, int n) {
    __shared__ _Float16 W2T[128 * 136];    // [n][k], stride 136
    __shared__ _Float16 outs[64 * 136];    // [node][feat], stride 136
    int tid = threadIdx.x;
    for (int i = tid; i < 128 * 16; i += 256) {
        int r = i >> 4, q = i & 15;
        *(uint4*)&W2T[r * 136 + q * 8] = ((const uint4*)W2Th)[r * 16 + q];
    }
    int base = blockIdx.x * 64;
    int lane = tid & 63, wid = tid >> 6;
    int l15 = lane & 15, quad = lane >> 4;
    int arow = base + wid * 16 + l15;
    if (arow >= n) arow = n - 1;           // clamp: safe reads, invalid rows unwritten
    const _Float16* Aptr = (const _Float16*)h1h + (size_t)arow * 128;
    floatx4 acc[8];
#pragma unroll
    for (int t = 0; t < 8; ++t) acc[t] = (floatx4){0.f, 0.f, 0.f, 0.f};
    __syncthreads();
#pragma unroll
    for (int c = 0; c < 4; ++c) {
        half8 a = *(const half8*)(Aptr + c * 32 + quad * 8);
#pragma unroll
        for (int t = 0; t < 8; ++t) {
            half8 b = *(const half8*)(&W2T[(t * 16 + l15) * 136 + c * 32 + quad * 8]);
            acc[t] = __builtin_amdgcn_mfma_f32_16x16x32_f16(a, b, acc[t], 0, 0, 0);
        }
    }
    float dv[4];
#pragma unroll
    for (int r = 0; r < 4; ++r) {
        int nd = base + wid * 16 + quad * 4 + r;
        dv[r] = dinv[(nd < n) ? nd : 0];
    }
#pragma unroll
    for (int t = 0; t < 8; ++t)
#pragma unroll
        for (int r = 0; r < 4; ++r)
            outs[(wid * 16 + quad * 4 + r) * 136 + t * 16 + l15] = (_Float16)(acc[t][r] * dv[r]);
    __syncthreads();
    for (int i = tid; i < 64 * 16; i += 256) {
        int ln = i >> 4, qq = i & 15;
        long nd = base + ln;
        if (nd < n) {
            uint4 u = *(uint4*)&outs[ln * 136 + qq * 8];
            ((uint4*)hsh)[nd * 16 + qq] = u;
        }
    }
}

// ---------------- 128-wide agg (layer 2): half in, half out ----------------

__global__ void agg128h_kernel(const __half* __restrict__ hsh, const int2* __restrict__ begend,
                               const unsigned short* __restrict__ csr16, const float* __restrict__ dinv,
                               const float* __restrict__ bias, __half* __restrict__ outh, int n) {
    int node = (int)(((long)blockIdx.x * blockDim.x + threadIdx.x) >> 6);
    int lane = threadIdx.x & 63;
    if (node >= n) return;
    int grp = lane >> 5, q = lane & 31;
    int2 be = begend[node];
    int beg = be.x, end = be.y;
    float4 acc = make_float4(0.f, 0.f, 0.f, 0.f);
    int eb = beg;
    for (; eb + 16 <= end; eb += 16) {
        int s[8]; uint2 u[8];
#pragma unroll
        for (int j = 0; j < 8; ++j) s[j] = csr16[eb + grp + 2 * j];
#pragma unroll
        for (int j = 0; j < 8; ++j) u[j] = ((const uint2*)hsh)[(long)s[j] * 32 + q];
#pragma unroll
        for (int j = 0; j < 8; ++j) {
            float2 lo = __half22float2(*(__half2*)&u[j].x);
            float2 hi = __half22float2(*(__half2*)&u[j].y);
            acc.x += lo.x; acc.y += lo.y; acc.z += hi.x; acc.w += hi.y;
        }
    }
    if (eb + 8 <= end) {
        int s[4]; uint2 u[4];
#pragma unroll
        for (int j = 0; j < 4; ++j) s[j] = csr16[eb + grp + 2 * j];
#pragma unroll
        for (int j = 0; j < 4; ++j) u[j] = ((const uint2*)hsh)[(long)s[j] * 32 + q];
#pragma unroll
        for (int j = 0; j < 4; ++j) {
            float2 lo = __half22float2(*(__half2*)&u[j].x);
            float2 hi = __half22float2(*(__half2*)&u[j].y);
            acc.x += lo.x; acc.y += lo.y; acc.z += hi.x; acc.w += hi.y;
        }
        eb += 8;
    }
    for (int e = eb + grp; e < end; e += 2) {
        uint2 u = ((const uint2*)hsh)[(long)csr16[e] * 32 + q];
        float2 lo = __half22float2(*(__half2*)&u.x);
        float2 hi = __half22float2(*(__half2*)&u.y);
        acc.x += lo.x; acc.y += lo.y; acc.z += hi.x; acc.w += hi.y;
    }
    acc.x += __shfl_down(acc.x, 32);
    acc.y += __shfl_down(acc.y, 32);
    acc.z += __shfl_down(acc.z, 32);
    acc.w += __shfl_down(acc.w, 32);
    if (grp == 0) {
        float di = dinv[node];
        float4 b = ((const float4*)bias)[q];
        __half2 h01 = __floats2half2_rn(fmaxf(acc.x * di + b.x, 0.f), fmaxf(acc.y * di + b.y, 0.f));
        __half2 h23 = __floats2half2_rn(fmaxf(acc.z * di + b.z, 0.f), fmaxf(acc.w * di + b.w, 0.f));
        uint2 u = make_uint2(*(unsigned int*)&h01, *(unsigned int*)&h23);
        ((uint2*)outh)[(long)node * 32 + q] = u;
    }
}

// ---------------- folded layer 3 + pool + head ----------------

// y32h[n,32] = (h2h @ W3l)*dinv, cols 19..31 zero; 12 nodes/block; h2 fp16 in
__global__ void gemm_y32h_kernel(const __half* __restrict__ h2h, const float* __restrict__ W3l,
                                 const float* __restrict__ dinv, __half* __restrict__ ys, int n) {
    __shared__ float hs[12][HIDDEN];
    __shared__ float Ws[HIDDEN][20];
    int tid = threadIdx.x;
    long base = (long)blockIdx.x * 12;
    for (int i = tid; i < HIDDEN * NCLS; i += 256) Ws[i / NCLS][i % NCLS] = W3l[i];
    for (int idx = tid; idx < 12 * 32; idx += 256) {
        int node = idx >> 5, q = idx & 31;
        long gn = base + node;
        uint2 u = (gn < n) ? ((const uint2*)h2h)[gn * 32 + q] : make_uint2(0u, 0u);
        float2 lo = __half22float2(*(__half2*)&u.x);
        float2 hi = __half22float2(*(__half2*)&u.y);
        hs[node][q * 4] = lo.x; hs[node][q * 4 + 1] = lo.y;
        hs[node][q * 4 + 2] = hi.x; hs[node][q * 4 + 3] = hi.y;
    }
    __syncthreads();
    if (tid < 12 * NCLS) {
        int node = tid / NCLS, j = tid % NCLS;
        long gn = base + node;
        if (gn < n) {
            float acc = 0.f;
#pragma unroll 8
            for (int k = 0; k < HIDDEN; ++k) acc += hs[node][k] * Ws[k][j];
            ys[gn * 32 + j] = __float2half(acc * dinv[gn]);
        }
    }
    for (int idx = tid; idx < 12 * 13; idx += 256) {
        int node = idx / 13, j = 19 + idx % 13;
        long gn = base + node;
        if (gn < n) ys[gn * 32 + j] = __half(0.f);
    }
}

__global__ void agg24h_pool_kernel(const __half* __restrict__ ys, const int2* __restrict__ begend,
                                   const unsigned short* __restrict__ csr16, const float* __restrict__ dinv,
                                   const int* __restrict__ batch, float* __restrict__ pool, int n) {
    int node = (int)(((long)blockIdx.x * blockDim.x + threadIdx.x) >> 6);
    int lane = threadIdx.x & 63;
    if (node >= n) return;
    int grp = lane >> 4, f = lane & 15;
    int2 be = begend[node];
    int beg = be.x, end = be.y;
    float2 acc = {0.f, 0.f};
    int eb = beg;
    for (; eb + 32 <= end; eb += 32) {
        int s[8]; unsigned int u[8];
#pragma unroll
        for (int j = 0; j < 8; ++j) s[j] = csr16[eb + grp + 4 * j];
#pragma unroll
        for (int j = 0; j < 8; ++j) u[j] = ((const unsigned int*)ys)[(long)s[j] * 16 + f];
#pragma unroll
        for (int j = 0; j < 8; ++j) {
            float2 v = __half22float2(*(__half2*)&u[j]);
            acc.x += v.x; acc.y += v.y;
        }
    }
    if (eb + 16 <= end) {
        int s[4]; unsigned int u[4];
#pragma unroll
        for (int j = 0; j < 4; ++j) s[j] = csr16[eb + grp + 4 * j];
#pragma unroll
        for (int j = 0; j < 4; ++j) u[j] = ((const unsigned int*)ys)[(long)s[j] * 16 + f];
#pragma unroll
        for (int j = 0; j < 4; ++j) {
            float2 v = __half22float2(*(__half2*)&u[j]);
            acc.x += v.x; acc.y += v.y;
        }
        eb += 16;
    }
    for (int e = eb + grp; e < end; e += 4) {
        unsigned int u = ((const unsigned int*)ys)[(long)csr16[e] * 16 + f];
        float2 v = __half22float2(*(__half2*)&u);
        acc.x += v.x; acc.y += v.y;
    }
    acc.x += __shfl_down(acc.x, 32);
    acc.y += __shfl_down(acc.y, 32);
    acc.x += __shfl_down(acc.x, 16);
    acc.y += __shfl_down(acc.y, 16);
    if (lane < 16) {
        int g = batch[node];
        float sc = dinv[node];
        int c0 = 2 * f;
        if (c0 < NCLS) atomicAdd(&pool[(long)g * 24 + c0], acc.x * sc);
        if (c0 + 1 < NCLS) atomicAdd(&pool[(long)g * 24 + c0 + 1], acc.y * sc);
    }
}

__global__ void final_kernel(const float* __restrict__ pool, const float* __restrict__ cnt,
                             const float* __restrict__ b3l, const float* __restrict__ bl,
                             float* __restrict__ out, int G) {
    int i = blockIdx.x * blockDim.x + threadIdx.x;
    if (i >= G * NCLS) return;
    int g = i / NCLS, j = i % NCLS;
    float c = cnt[g];
    out[i] = (c > 0.f) ? pool[(long)g * 24 + j] / c + b3l[j] + bl[j] : bl[j];
}

// ---------------- launch ----------------

static inline size_t align256(size_t x) { return (x + 255) & ~(size_t)255; }

extern "C" void kernel_launch(void* const* d_in, const int* in_sizes, int n_in,
                              void* d_out, int out_size, void* d_ws, size_t ws_size,
                              hipStream_t stream) {
    const float* x    = (const float*)d_in[0];
    const int*   ei   = (const int*)d_in[1];
    const int*   batch= (const int*)d_in[2];
    const float* W1   = (const float*)d_in[3];
    const float* b1   = (const float*)d_in[4];
    const float* W2   = (const float*)d_in[5];
    const float* b2   = (const float*)d_in[6];
    const float* W3   = (const float*)d_in[7];
    const float* b3   = (const float*)d_in[8];
    const float* Wl   = (const float*)d_in[9];
    const float* bl   = (const float*)d_in[10];
    float* out = (float*)d_out;

    const int N = in_sizes[0] / F_IN;
    const int E = in_sizes[1] / 2;
    const int G = out_size / NCLS;
    const int* src = ei;
    const int* dst = ei + E;
    const int nSB = (E + EPB - 1) / EPB;
    const int nBK = (N + RNODES - 1) / RNODES;
    // cap: mean edges per USED bucket = E*RNODES/N; +768 (~12 sigma) slack
    int cap = (int)((long long)E * RNODES / N) + 768;
    if (cap + RNODES > OUTL_CAP) cap = OUTL_CAP - RNODES;
    const int rst = cap + RNODES;

    // workspace carve-up
    char* p = (char*)d_ws;
    size_t off = 0;
    unsigned int*   bents  = (unsigned int*)(p + off);   off = align256(off + (size_t)NB * cap * 4);
    unsigned short* csr16  = (unsigned short*)(p + off); off = align256(off + (size_t)NB * rst * 2);
    int2*           begend = (int2*)(p + off);           off = align256(off + (size_t)N * 8);
    float*          dinv   = (float*)(p + off);          off = align256(off + (size_t)N * 4);
    __half*         x16h   = (__half*)(p + off);         off = align256(off + (size_t)N * 16 * 2);
    __half*         h1h    = (__half*)(p + off);         off = align256(off + (size_t)N * HIDDEN * 2);
    __half*         hsh    = (__half*)(p + off);         off = align256(off + (size_t)N * HIDDEN * 2);
    __half*         h2h    = (__half*)(p + off);         off = align256(off + (size_t)N * HIDDEN * 2);
    __half*         y32h   = (__half*)(p + off);         off = align256(off + (size_t)N * 32 * 2);
    __half*         W2Th   = (__half*)(p + off);         off = align256(off + (size_t)HIDDEN * HIDDEN * 2);
    float*          W3l    = (float*)(p + off);          off = align256(off + (size_t)HIDDEN * NCLS * 4);
    float*          b3l    = (float*)(p + off);          off = align256(off + (size_t)NCLS * 4);
    float*          pool   = (float*)(p + off);
    float*          gcnt   = pool + (size_t)G * 24;
    int*            bcur   = (int*)(pool + (size_t)G * 25);  // adjacent: one memset covers all
    off = align256(off + (size_t)G * 25 * 4 + NB * 4);
    (void)ws_size; (void)n_in;

    // one memset zeroes pool, gcnt, and bcur
    hipMemsetAsync(pool, 0, (size_t)G * 25 * 4 + NB * 4, stream);

    // CSR build (scatter includes w3l + W2 fp16 conversion as extra blocks)
    scatter_kernel<<<nSB + 15, 256, 0, stream>>>(src, dst, bcur, bents, E, cap, nSB,
                                                 W3, Wl, b3, W3l, b3l, W2, W2Th);
    build_kernel<<<nBK, 512, 0, stream>>>(bents, bcur, x, batch, begend, csr16,
                                          dinv, gcnt, x16h, N, cap, rst);

    const int aggBlocks = (N + 3) / 4;  // 4 waves/block, wave per node

    // layer 1 fused: h1 = relu((dinv*sum x16h)@W1 + b1) -> fp16
    agg16_gemm_kernel<<<aggBlocks, 256, 0, stream>>>(x16h, begend, csr16, dinv, W1, b1, h1h, N);

    // layer 2: hsh = half((h1@W2)*dinv) row-major [MFMA] ; h2h = relu(dinv*sum + b2) fp16
    gemm_mfma_kernel<<<(N + 63) / 64, 256, 0, stream>>>(h1h, W2Th, dinv, hsh, N);
    agg128h_kernel<<<aggBlocks, 256, 0, stream>>>(hsh, begend, csr16, dinv, b2, h2h, N);

    // folded layer 3 + pool
    gemm_y32h_kernel<<<(N + 11) / 12, 256, 0, stream>>>(h2h, W3l, dinv, y32h, N);
    agg24h_pool_kernel<<<aggBlocks, 256, 0, stream>>>(y32h, begend, csr16, dinv, batch, pool, N);
    final_kernel<<<(G * NCLS + 255) / 256, 256, 0, stream>>>(pool, gcnt, b3l, bl, out, G);
}